// Round 1
// baseline (2109.555 us; speedup 1.0000x reference)
//
#include <hip/hip_runtime.h>

#define M_MOLS  10000
#define NA      32     // atoms per molecule
#define E_MOL   64
#define IN_CH   64
#define OUT_CH  128
#define HID     256
#define E_KG    320000
#define KG_N    10000

// ---------------------------------------------------------------------------
// Molecule GNN: one block per molecule. 3x (GEMM -> normalized aggregation)
// then min-pool over atoms. Aggregation is a dense 32x32 matmul against
// B[s][i] = norm(edge s->i) (+ dinv^2 on the diagonal), built once per block.
// ---------------------------------------------------------------------------
__global__ __launch_bounds__(256, 2) void mol_kernel(
    const float* __restrict__ mol_x, const int* __restrict__ mol_ei,
    const float* __restrict__ W1, const float* __restrict__ b1,
    const float* __restrict__ W2, const float* __restrict__ b2,
    const float* __restrict__ W3, const float* __restrict__ b3,
    float* __restrict__ embed)
{
    __shared__ float xs[NA * IN_CH];    // 8 KB   input features
    __shared__ float A [NA * HID];      // 32 KB  GEMM output (xw)
    __shared__ float Hs[NA * HID];      // 32 KB  aggregated/activated
    __shared__ float B [NA * NA];       // 4 KB   B[s][i] = edge weight s->i
    __shared__ int   se[E_MOL], de[E_MOL];
    __shared__ float dinv[NA];
    __shared__ int   deg[NA];

    const int t   = threadIdx.x;
    const int mol = blockIdx.x;

    // ---- load x (2048 floats, coalesced float4) ----
    {
        const float4* src = (const float4*)(mol_x + (size_t)mol * (NA * IN_CH));
        float4* dst = (float4*)xs;
        dst[t]       = src[t];
        dst[t + 256] = src[t + 256];
    }
    // ---- load edges ----
    {
        const int* eb = mol_ei + (size_t)mol * (2 * E_MOL);
        if (t < E_MOL)            se[t]          = eb[t];
        else if (t < 2 * E_MOL)   de[t - E_MOL]  = eb[t];
    }
    if (t < NA) deg[t] = 1;                 // self loop
    for (int i = t; i < NA * NA; i += 256) B[i] = 0.f;
    __syncthreads();

    if (t < E_MOL) atomicAdd(&deg[de[t]], 1);
    __syncthreads();
    if (t < NA) dinv[t] = rsqrtf((float)deg[t]);
    __syncthreads();
    if (t < E_MOL) {
        int s = se[t], d = de[t];
        atomicAdd(&B[s * NA + d], dinv[s] * dinv[d]);
    } else if (t < E_MOL + NA) {
        int i = t - E_MOL;
        atomicAdd(&B[i * NA + i], dinv[i] * dinv[i]);
    }
    __syncthreads();

    // ================= Layer 1 GEMM: A = xs @ W1  (K=64, C=256) ============
    {
        const int c = t;
        float acc[NA];
        #pragma unroll
        for (int i = 0; i < NA; ++i) acc[i] = 0.f;
        float w0n = W1[0 * HID + c], w1n = W1[1 * HID + c],
              w2n = W1[2 * HID + c], w3n = W1[3 * HID + c];
        for (int k = 0; k < IN_CH; k += 4) {
            const float w0 = w0n, w1 = w1n, w2 = w2n, w3 = w3n;
            const int kn = (k + 4 < IN_CH) ? (k + 4) : k;   // branchless prefetch
            w0n = W1[(kn + 0) * HID + c]; w1n = W1[(kn + 1) * HID + c];
            w2n = W1[(kn + 2) * HID + c]; w3n = W1[(kn + 3) * HID + c];
            #pragma unroll
            for (int i = 0; i < NA; ++i) {
                float4 h4 = *(const float4*)&xs[i * IN_CH + k];
                acc[i] = fmaf(h4.x, w0, fmaf(h4.y, w1, fmaf(h4.z, w2, fmaf(h4.w, w3, acc[i]))));
            }
        }
        #pragma unroll
        for (int i = 0; i < NA; ++i) A[i * HID + c] = acc[i];
    }
    __syncthreads();

    // ---- Agg 1: Hs = relu(B^T @ A + b1) ----
    {
        const int c = t;
        float acc[NA];
        #pragma unroll
        for (int i = 0; i < NA; ++i) acc[i] = 0.f;
        for (int s = 0; s < NA; ++s) {
            const float av = A[s * HID + c];
            #pragma unroll
            for (int i = 0; i < NA; i += 4) {
                float4 b4 = *(const float4*)&B[s * NA + i];
                acc[i + 0] = fmaf(b4.x, av, acc[i + 0]);
                acc[i + 1] = fmaf(b4.y, av, acc[i + 1]);
                acc[i + 2] = fmaf(b4.z, av, acc[i + 2]);
                acc[i + 3] = fmaf(b4.w, av, acc[i + 3]);
            }
        }
        const float bc = b1[c];
        #pragma unroll
        for (int i = 0; i < NA; ++i) {
            float v = acc[i] + bc;
            Hs[i * HID + c] = v > 0.f ? v : 0.f;
        }
    }
    __syncthreads();

    // ================= Layer 2 GEMM: A = Hs @ W2  (K=256, C=256) ===========
    {
        const int c = t;
        float acc[NA];
        #pragma unroll
        for (int i = 0; i < NA; ++i) acc[i] = 0.f;
        float w0n = W2[0 * HID + c], w1n = W2[1 * HID + c],
              w2n = W2[2 * HID + c], w3n = W2[3 * HID + c];
        for (int k = 0; k < HID; k += 4) {
            const float w0 = w0n, w1 = w1n, w2 = w2n, w3 = w3n;
            const int kn = (k + 4 < HID) ? (k + 4) : k;
            w0n = W2[(kn + 0) * HID + c]; w1n = W2[(kn + 1) * HID + c];
            w2n = W2[(kn + 2) * HID + c]; w3n = W2[(kn + 3) * HID + c];
            #pragma unroll
            for (int i = 0; i < NA; ++i) {
                float4 h4 = *(const float4*)&Hs[i * HID + k];
                acc[i] = fmaf(h4.x, w0, fmaf(h4.y, w1, fmaf(h4.z, w2, fmaf(h4.w, w3, acc[i]))));
            }
        }
        __syncthreads();   // all reads of Hs done before agg overwrites it
        #pragma unroll
        for (int i = 0; i < NA; ++i) A[i * HID + c] = acc[i];
    }
    __syncthreads();

    // ---- Agg 2: Hs = relu(B^T @ A + b2) ----
    {
        const int c = t;
        float acc[NA];
        #pragma unroll
        for (int i = 0; i < NA; ++i) acc[i] = 0.f;
        for (int s = 0; s < NA; ++s) {
            const float av = A[s * HID + c];
            #pragma unroll
            for (int i = 0; i < NA; i += 4) {
                float4 b4 = *(const float4*)&B[s * NA + i];
                acc[i + 0] = fmaf(b4.x, av, acc[i + 0]);
                acc[i + 1] = fmaf(b4.y, av, acc[i + 1]);
                acc[i + 2] = fmaf(b4.z, av, acc[i + 2]);
                acc[i + 3] = fmaf(b4.w, av, acc[i + 3]);
            }
        }
        const float bc = b2[c];
        #pragma unroll
        for (int i = 0; i < NA; ++i) {
            float v = acc[i] + bc;
            Hs[i * HID + c] = v > 0.f ? v : 0.f;
        }
    }
    __syncthreads();

    // ================= Layer 3 GEMM: A = Hs @ W3  (K=256, C=128) ===========
    {
        const int c  = t & 127;
        const int i0 = (t >> 7) * 16;          // rows [i0, i0+16)
        float acc[16];
        #pragma unroll
        for (int i = 0; i < 16; ++i) acc[i] = 0.f;
        float w0n = W3[0 * OUT_CH + c], w1n = W3[1 * OUT_CH + c],
              w2n = W3[2 * OUT_CH + c], w3n = W3[3 * OUT_CH + c];
        for (int k = 0; k < HID; k += 4) {
            const float w0 = w0n, w1 = w1n, w2 = w2n, w3 = w3n;
            const int kn = (k + 4 < HID) ? (k + 4) : k;
            w0n = W3[(kn + 0) * OUT_CH + c]; w1n = W3[(kn + 1) * OUT_CH + c];
            w2n = W3[(kn + 2) * OUT_CH + c]; w3n = W3[(kn + 3) * OUT_CH + c];
            #pragma unroll
            for (int i = 0; i < 16; ++i) {
                float4 h4 = *(const float4*)&Hs[(i0 + i) * HID + k];
                acc[i] = fmaf(h4.x, w0, fmaf(h4.y, w1, fmaf(h4.z, w2, fmaf(h4.w, w3, acc[i]))));
            }
        }
        __syncthreads();   // all reads of Hs done before agg3 overwrites it
        #pragma unroll
        for (int i = 0; i < 16; ++i) A[(i0 + i) * OUT_CH + c] = acc[i];
    }
    __syncthreads();

    // ---- Agg 3 (no relu): Hs = B^T @ A + b3, stride 128 ----
    {
        const int c  = t & 127;
        const int i0 = (t >> 7) * 16;
        float acc[16];
        #pragma unroll
        for (int i = 0; i < 16; ++i) acc[i] = 0.f;
        for (int s = 0; s < NA; ++s) {
            const float av = A[s * OUT_CH + c];
            #pragma unroll
            for (int i = 0; i < 16; i += 4) {
                float4 b4 = *(const float4*)&B[s * NA + i0 + i];
                acc[i + 0] = fmaf(b4.x, av, acc[i + 0]);
                acc[i + 1] = fmaf(b4.y, av, acc[i + 1]);
                acc[i + 2] = fmaf(b4.z, av, acc[i + 2]);
                acc[i + 3] = fmaf(b4.w, av, acc[i + 3]);
            }
        }
        const float bc = b3[c];
        #pragma unroll
        for (int i = 0; i < 16; ++i) Hs[(i0 + i) * OUT_CH + c] = acc[i] + bc;
    }
    __syncthreads();

    // ---- min-pool over atoms -> embed[mol] ----
    if (t < OUT_CH) {
        float m = Hs[0 * OUT_CH + t];
        #pragma unroll
        for (int i = 1; i < NA; ++i) m = fminf(m, Hs[i * OUT_CH + t]);
        embed[(size_t)mol * OUT_CH + t] = m;
    }
}

// ---------------------------------------------------------------------------
// KG graph: CSR build (count -> scan -> fill), then GEMM + gather-aggregate.
// ---------------------------------------------------------------------------
__global__ void kg_count(const int* __restrict__ kg_ei, int* __restrict__ degi) {
    int e = blockIdx.x * 256 + threadIdx.x;
    if (e < E_KG) atomicAdd(&degi[kg_ei[E_KG + e]], 1);
}

__global__ void kg_dinv(const int* __restrict__ degi, float* __restrict__ dinvk) {
    int i = blockIdx.x * 256 + threadIdx.x;
    if (i < KG_N) dinvk[i] = rsqrtf((float)(degi[i] + 1));   // +1 self loop
}

__global__ __launch_bounds__(1024) void scan_kernel(const int* __restrict__ degi,
                                                    int* __restrict__ ptr, int n) {
    __shared__ int buf[1024];
    __shared__ int carry;
    const int t = threadIdx.x;
    if (t == 0) { carry = 0; ptr[0] = 0; }
    __syncthreads();
    for (int base = 0; base < n; base += 1024) {
        const int i = base + t;
        int v = (i < n) ? degi[i] : 0;
        buf[t] = v;
        __syncthreads();
        for (int off = 1; off < 1024; off <<= 1) {
            int add = (t >= off) ? buf[t - off] : 0;
            __syncthreads();
            buf[t] += add;
            __syncthreads();
        }
        if (i < n) ptr[i + 1] = carry + buf[t];
        __syncthreads();
        if (t == 0) carry += buf[1023];
        __syncthreads();
    }
}

__global__ void kg_fill(const int* __restrict__ kg_ei, const int* __restrict__ ptr,
                        int* __restrict__ cursor, int* __restrict__ csr) {
    int e = blockIdx.x * 256 + threadIdx.x;
    if (e < E_KG) {
        int s = kg_ei[e];
        int d = kg_ei[E_KG + e];
        int pos = atomicAdd(&cursor[d], 1);
        csr[ptr[d] + pos] = s;
    }
}

// Y[r][c] = dinv[r] * sum_k X[r][k] * W[k][c]   (X: [N][128], W: [128][256])
__global__ __launch_bounds__(256) void kg_gemm1(const float* __restrict__ X,
                                                const float* __restrict__ W,
                                                const float* __restrict__ dinvk,
                                                float* __restrict__ Y) {
    __shared__ float es[4 * OUT_CH];   // 4 rows x 128
    const int t  = threadIdx.x;
    const int r0 = blockIdx.x * 4;
    if (t < 128) ((float4*)es)[t] = ((const float4*)(X + (size_t)r0 * OUT_CH))[t];
    __syncthreads();
    const int c = t;
    float a0 = 0.f, a1 = 0.f, a2 = 0.f, a3 = 0.f;
    for (int k = 0; k < OUT_CH; k += 4) {
        const float w0 = W[(k + 0) * HID + c], w1 = W[(k + 1) * HID + c],
                    w2 = W[(k + 2) * HID + c], w3 = W[(k + 3) * HID + c];
        float4 e0 = *(const float4*)&es[0 * OUT_CH + k];
        float4 e1 = *(const float4*)&es[1 * OUT_CH + k];
        float4 e2 = *(const float4*)&es[2 * OUT_CH + k];
        float4 e3 = *(const float4*)&es[3 * OUT_CH + k];
        a0 = fmaf(e0.x, w0, fmaf(e0.y, w1, fmaf(e0.z, w2, fmaf(e0.w, w3, a0))));
        a1 = fmaf(e1.x, w0, fmaf(e1.y, w1, fmaf(e1.z, w2, fmaf(e1.w, w3, a1))));
        a2 = fmaf(e2.x, w0, fmaf(e2.y, w1, fmaf(e2.z, w2, fmaf(e2.w, w3, a2))));
        a3 = fmaf(e3.x, w0, fmaf(e3.y, w1, fmaf(e3.z, w2, fmaf(e3.w, w3, a3))));
    }
    Y[(size_t)(r0 + 0) * HID + c] = dinvk[r0 + 0] * a0;
    Y[(size_t)(r0 + 1) * HID + c] = dinvk[r0 + 1] * a1;
    Y[(size_t)(r0 + 2) * HID + c] = dinvk[r0 + 2] * a2;
    Y[(size_t)(r0 + 3) * HID + c] = dinvk[r0 + 3] * a3;
}

// Y[r][c] = dinv[r] * sum_k X[r][k] * W[k][c]   (X: [N][256], W: [256][128])
__global__ __launch_bounds__(256) void kg_gemm2(const float* __restrict__ X,
                                                const float* __restrict__ W,
                                                const float* __restrict__ dinvk,
                                                float* __restrict__ Y) {
    __shared__ float es[8 * HID];      // 8 rows x 256
    const int t  = threadIdx.x;
    const int r0 = blockIdx.x * 8;
    {
        const float4* src = (const float4*)(X + (size_t)r0 * HID);
        float4* dst = (float4*)es;
        dst[t]       = src[t];
        dst[t + 256] = src[t + 256];
    }
    __syncthreads();
    const int c   = t & 127;
    const int rr0 = (t >> 7) * 4;      // rows [rr0, rr0+4) of the 8
    float acc[4] = {0.f, 0.f, 0.f, 0.f};
    for (int k = 0; k < HID; k += 4) {
        const float w0 = W[(k + 0) * OUT_CH + c], w1 = W[(k + 1) * OUT_CH + c],
                    w2 = W[(k + 2) * OUT_CH + c], w3 = W[(k + 3) * OUT_CH + c];
        #pragma unroll
        for (int r = 0; r < 4; ++r) {
            float4 e = *(const float4*)&es[(rr0 + r) * HID + k];
            acc[r] = fmaf(e.x, w0, fmaf(e.y, w1, fmaf(e.z, w2, fmaf(e.w, w3, acc[r]))));
        }
    }
    #pragma unroll
    for (int r = 0; r < 4; ++r)
        Y[(size_t)(r0 + rr0 + r) * OUT_CH + c] = dinvk[r0 + rr0 + r] * acc[r];
}

// out[n][c] = [relu] dinv[n] * (xw[n][c] + sum_{s in in(n)} xw[s][c]) + bias[c]
// (xw rows are pre-scaled by dinv[src])
template <int C, bool RELU>
__global__ __launch_bounds__(C) void kg_agg_kernel(
    const float* __restrict__ xw, const float* __restrict__ dinvk,
    const int* __restrict__ ptr, const int* __restrict__ csr,
    const float* __restrict__ bias, float* __restrict__ out)
{
    const int n = blockIdx.x;
    const int c = threadIdx.x;
    const int e1 = ptr[n + 1];
    int e = ptr[n];
    float acc = xw[(size_t)n * C + c];                 // self contribution
    int sn = (e < e1) ? csr[e] : 0;
    while (e < e1) {
        const int s = sn;
        ++e;
        sn = (e < e1) ? csr[e] : 0;                    // prefetch next index
        acc += xw[(size_t)s * C + c];
    }
    float v = fmaf(dinvk[n], acc, bias[c]);
    if (RELU) v = v > 0.f ? v : 0.f;
    out[(size_t)n * C + c] = v;
}

// ---------------------------------------------------------------------------
extern "C" void kernel_launch(void* const* d_in, const int* in_sizes, int n_in,
                              void* d_out, int out_size, void* d_ws, size_t ws_size,
                              hipStream_t stream) {
    const float* mol_x  = (const float*)d_in[0];
    const int*   mol_ei = (const int*)  d_in[1];
    const int*   kg_ei  = (const int*)  d_in[2];
    const float* W1 = (const float*)d_in[3];  const float* b1 = (const float*)d_in[4];
    const float* W2 = (const float*)d_in[5];  const float* b2 = (const float*)d_in[6];
    const float* W3 = (const float*)d_in[7];  const float* b3 = (const float*)d_in[8];
    const float* Wk1 = (const float*)d_in[9];  const float* bk1 = (const float*)d_in[10];
    const float* Wk2 = (const float*)d_in[11]; const float* bk2 = (const float*)d_in[12];
    float* out = (float*)d_out;

    char* ws = (char*)d_ws;
    size_t off = 0;
    auto alloc = [&](size_t bytes) -> void* {
        void* p = ws + off;
        off += (bytes + 255) & ~(size_t)255;
        return p;
    };
    float* embed = (float*)alloc((size_t)M_MOLS * OUT_CH * 4);
    float* xw1   = (float*)alloc((size_t)KG_N * HID * 4);
    float* h1    = (float*)alloc((size_t)KG_N * HID * 4);
    float* xw2   = (float*)alloc((size_t)KG_N * OUT_CH * 4);
    int*   degi  = (int*)  alloc((size_t)KG_N * 4);
    float* dinvk = (float*)alloc((size_t)KG_N * 4);
    int*   ptr   = (int*)  alloc((size_t)(KG_N + 4) * 4);
    int*   cursor= (int*)  alloc((size_t)KG_N * 4);
    int*   csr   = (int*)  alloc((size_t)E_KG * 4);

    hipMemsetAsync(degi,   0, (size_t)KG_N * 4, stream);
    hipMemsetAsync(cursor, 0, (size_t)KG_N * 4, stream);

    // Phase A: molecule GNN -> embed [10000, 128]
    mol_kernel<<<M_MOLS, 256, 0, stream>>>(mol_x, mol_ei, W1, b1, W2, b2, W3, b3, embed);

    // Phase B: CSR build for KG graph
    kg_count<<<(E_KG + 255) / 256, 256, 0, stream>>>(kg_ei, degi);
    scan_kernel<<<1, 1024, 0, stream>>>(degi, ptr, KG_N);
    kg_dinv<<<(KG_N + 255) / 256, 256, 0, stream>>>(degi, dinvk);
    kg_fill<<<(E_KG + 255) / 256, 256, 0, stream>>>(kg_ei, ptr, cursor, csr);

    // KG layer 1: relu(gcn(embed, Wk1) + bk1)
    kg_gemm1<<<KG_N / 4, 256, 0, stream>>>(embed, Wk1, dinvk, xw1);
    kg_agg_kernel<HID, true><<<KG_N, HID, 0, stream>>>(xw1, dinvk, ptr, csr, bk1, h1);

    // KG layer 2: gcn(h1, Wk2) + bk2 -> out
    kg_gemm2<<<KG_N / 8, 256, 0, stream>>>(h1, Wk2, dinvk, xw2);
    kg_agg_kernel<OUT_CH, false><<<KG_N, OUT_CH, 0, stream>>>(xw2, dinvk, ptr, csr, bk2, out);
}

// Round 2
// 854.201 us; speedup vs baseline: 2.4696x; 2.4696x over previous
//
#include <hip/hip_runtime.h>

#define M_MOLS  10000
#define NA      32     // atoms per molecule
#define E_MOL   64
#define IN_CH   64
#define OUT_CH  128
#define HID     256
#define E_KG    320000
#define KG_N    10000

typedef __attribute__((ext_vector_type(8))) short  s16x8;  // 8 bf16 (4 VGPR)
typedef __attribute__((ext_vector_type(4))) short  s16x4;  // 4 bf16 (8B)
typedef __attribute__((ext_vector_type(4))) float  f32x4;

// RNE float -> bf16 bits (finite inputs only)
static __device__ __forceinline__ short f2bf(float f) {
    unsigned u = __float_as_uint(f);
    u += 0x7FFFu + ((u >> 16) & 1u);
    return (short)(u >> 16);
}

// ---------------------------------------------------------------------------
// Weight prep: WT[c][k] = bf16(W[k][c])  (transposed so B-fragments are
// 8-contiguous-along-K per lane)
// ---------------------------------------------------------------------------
__global__ void prep_wt(const float* __restrict__ W, short* __restrict__ WT,
                        int K, int C, int total) {
    int idx = blockIdx.x * 256 + threadIdx.x;
    if (idx < total) {
        int c = idx / K, k = idx - c * K;
        WT[idx] = f2bf(W[k * C + c]);
    }
}

// ---------------------------------------------------------------------------
// Molecule GNN, all-MFMA. One block = one molecule, 4 waves.
// Wave mapping (GEMM & agg): rowg = wid&1 (16 atoms), col-halves by wid>>1.
// LDS: Hs[32][256] bf16 row-major, XOR-swizzled (byte ^= (row&7)<<4).
//      AT[256][40] bf16 = GEMM output transposed (AT[c][s]), 80B padded rows.
// GEMM:  D[rows 16][cols 16] tiles, A-frag from Hs, B-frag from global WT.
// AGG:   Hnext = BT(32x32) @ A(32xC): A-op = BT frags, B-op = AT frags.
// ---------------------------------------------------------------------------
__global__ __launch_bounds__(256, 3) void mol_kernel(
    const float* __restrict__ mol_x, const int* __restrict__ mol_ei,
    const short* __restrict__ WT1, const float* __restrict__ b1,
    const short* __restrict__ WT2, const float* __restrict__ b2,
    const short* __restrict__ WT3, const float* __restrict__ b3,
    float* __restrict__ embed)
{
    __shared__ short Hs[NA * HID];               // 16 KB
    __shared__ short AT[HID * 40];               // 20 KB
    __shared__ short BT[NA * 40];                // 2.5 KB  BT[i][s] bf16
    __shared__ float Bm[NA * NA];                // 4 KB    fp32 build buffer
    __shared__ float bias_s[2 * HID + OUT_CH];   // 640 floats
    __shared__ float minbuf[2 * OUT_CH];
    __shared__ int   se[E_MOL], de[E_MOL];
    __shared__ float dinv[NA];
    __shared__ int   deg[NA];

    const int t    = threadIdx.x;
    const int mol  = blockIdx.x;
    const int lane = t & 63;
    const int wid  = t >> 6;
    const int lr   = lane & 15;   // A-row / B-col index within tile
    const int lk   = lane >> 4;   // k-group (0..3)
    char* HsB = (char*)Hs;

    // ---- stage x -> Hs bf16 (rows 0..31, k 0..63), swizzled b128 writes ----
    {
        const float4* src = (const float4*)(mol_x + (size_t)mol * (NA * IN_CH));
        float4 a = src[t * 2], b = src[t * 2 + 1];
        s16x8 v;
        v[0] = f2bf(a.x); v[1] = f2bf(a.y); v[2] = f2bf(a.z); v[3] = f2bf(a.w);
        v[4] = f2bf(b.x); v[5] = f2bf(b.y); v[6] = f2bf(b.z); v[7] = f2bf(b.w);
        int row = t >> 3, k0 = (t & 7) * 8;
        int byte = (row << 9) + (k0 << 1); byte ^= (row & 7) << 4;
        *(s16x8*)(HsB + byte) = v;
    }
    // ---- edges, degrees, normalized adjacency ----
    {
        const int* eb = mol_ei + (size_t)mol * (2 * E_MOL);
        if (t < E_MOL)            se[t]         = eb[t];
        else if (t < 2 * E_MOL)   de[t - E_MOL] = eb[t];
    }
    if (t < NA) deg[t] = 1;                       // self loop
    for (int i = t; i < NA * NA; i += 256) Bm[i] = 0.f;
    __syncthreads();
    if (t < E_MOL) atomicAdd(&deg[de[t]], 1);
    __syncthreads();
    if (t < NA) dinv[t] = rsqrtf((float)deg[t]);
    __syncthreads();
    if (t < E_MOL) {
        atomicAdd(&Bm[se[t] * NA + de[t]], dinv[se[t]] * dinv[de[t]]);
    } else if (t < E_MOL + NA) {
        int i = t - E_MOL;
        atomicAdd(&Bm[i * NA + i], dinv[i] * dinv[i]);
    }
    for (int i = t; i < 2 * HID + OUT_CH; i += 256)
        bias_s[i] = (i < HID) ? b1[i] : (i < 2 * HID) ? b2[i - HID] : b3[i - 2 * HID];
    __syncthreads();
    // BT[i][s] = bf16(Bm[s][i])
    for (int i = t; i < NA * NA; i += 256) {
        int r = i >> 5, s = i & 31;
        BT[r * 40 + s] = f2bf(Bm[s * NA + r]);
    }
    __syncthreads();

    const int rowg = wid & 1;
    const int cb2  = (wid >> 1) * 128;  // layers 1,2: 8 col-tiles per wave
    const int cb3  = (wid >> 1) * 64;   // layer 3:    4 col-tiles per wave

    // ================= GEMM phase (templated via lambda-expansion) =========
#define GEMM_PHASE(WT, K, NCT, CB)                                             \
    {                                                                          \
        f32x4 acc[NCT];                                                        \
        _Pragma("unroll")                                                      \
        for (int c = 0; c < NCT; ++c) acc[c] = f32x4{0.f, 0.f, 0.f, 0.f};      \
        _Pragma("unroll 2")                                                    \
        for (int ks = 0; ks < (K) / 32; ++ks) {                                \
            int row = rowg * 16 + lr;                                          \
            int byte = (row << 9) + ((ks * 32 + lk * 8) << 1);                 \
            byte ^= (row & 7) << 4;                                            \
            s16x8 af = *(const s16x8*)(HsB + byte);                            \
            _Pragma("unroll")                                                  \
            for (int c = 0; c < NCT; ++c) {                                    \
                s16x8 bf = *(const s16x8*)((WT) +                              \
                    (size_t)((CB) + c * 16 + lr) * (K) + ks * 32 + lk * 8);    \
                acc[c] = __builtin_amdgcn_mfma_f32_16x16x32_bf16(af, bf,       \
                                                                 acc[c], 0, 0, 0); \
            }                                                                  \
        }                                                                      \
        int s0 = rowg * 16 + lk * 4;                                           \
        _Pragma("unroll")                                                      \
        for (int c = 0; c < NCT; ++c) {                                        \
            s16x4 v;                                                           \
            v[0] = f2bf(acc[c][0]); v[1] = f2bf(acc[c][1]);                    \
            v[2] = f2bf(acc[c][2]); v[3] = f2bf(acc[c][3]);                    \
            *(s16x4*)(AT + ((CB) + c * 16 + lr) * 40 + s0) = v;                \
        }                                                                      \
    }

    // ================= AGG phase: Hnext = BT @ A, + bias (+relu) ===========
#define AGG_PHASE(NCT, CB, BOFF, RELU)                                         \
    {                                                                          \
        s16x8 btf = *(const s16x8*)(BT + (rowg * 16 + lr) * 40 + lk * 8);      \
        _Pragma("unroll")                                                      \
        for (int c = 0; c < NCT; ++c) {                                        \
            s16x8 atf = *(const s16x8*)(AT + ((CB) + c * 16 + lr) * 40 + lk * 8); \
            f32x4 g = __builtin_amdgcn_mfma_f32_16x16x32_bf16(btf, atf,        \
                          f32x4{0.f, 0.f, 0.f, 0.f}, 0, 0, 0);                 \
            int col = (CB) + c * 16 + lr;                                      \
            float bc = bias_s[(BOFF) + col];                                   \
            _Pragma("unroll")                                                  \
            for (int j = 0; j < 4; ++j) {                                      \
                int i = rowg * 16 + lk * 4 + j;                                \
                float v = g[j] + bc;                                           \
                if (RELU) v = v > 0.f ? v : 0.f;                               \
                int byte = (i << 9) + (col << 1); byte ^= (i & 7) << 4;        \
                *(short*)(HsB + byte) = f2bf(v);                               \
            }                                                                  \
        }                                                                      \
    }

    GEMM_PHASE(WT1, IN_CH, 8, cb2)          // layer 1 GEMM  (K=64)
    __syncthreads();
    AGG_PHASE(8, cb2, 0, true)              // layer 1 agg + relu
    __syncthreads();
    GEMM_PHASE(WT2, HID, 8, cb2)            // layer 2 GEMM  (K=256)
    __syncthreads();
    AGG_PHASE(8, cb2, HID, true)            // layer 2 agg + relu
    __syncthreads();
    GEMM_PHASE(WT3, HID, 4, cb3)            // layer 3 GEMM  (K=256, C=128)
    __syncthreads();
    // ---- layer 3 agg (no relu) + min-pool in registers ----
    {
        s16x8 btf = *(const s16x8*)(BT + (rowg * 16 + lr) * 40 + lk * 8);
        #pragma unroll
        for (int c = 0; c < 4; ++c) {
            s16x8 atf = *(const s16x8*)(AT + (cb3 + c * 16 + lr) * 40 + lk * 8);
            f32x4 g = __builtin_amdgcn_mfma_f32_16x16x32_bf16(btf, atf,
                          f32x4{0.f, 0.f, 0.f, 0.f}, 0, 0, 0);
            int col = cb3 + c * 16 + lr;
            float bc = bias_s[2 * HID + col];
            float m = fminf(fminf(g[0], g[1]), fminf(g[2], g[3])) + bc;
            m = fminf(m, __shfl_xor(m, 16));
            m = fminf(m, __shfl_xor(m, 32));   // min over this wave's 16 rows
            if (lane < 16) minbuf[rowg * OUT_CH + col] = m;
        }
    }
    __syncthreads();
    if (t < OUT_CH)
        embed[(size_t)mol * OUT_CH + t] = fminf(minbuf[t], minbuf[OUT_CH + t]);
#undef GEMM_PHASE
#undef AGG_PHASE
}

// ---------------------------------------------------------------------------
// KG graph: CSR build (count -> scan -> fill), then GEMM + gather-aggregate.
// (unchanged from round 1 — measured negligible vs mol_kernel)
// ---------------------------------------------------------------------------
__global__ void kg_count(const int* __restrict__ kg_ei, int* __restrict__ degi) {
    int e = blockIdx.x * 256 + threadIdx.x;
    if (e < E_KG) atomicAdd(&degi[kg_ei[E_KG + e]], 1);
}

__global__ void kg_dinv(const int* __restrict__ degi, float* __restrict__ dinvk) {
    int i = blockIdx.x * 256 + threadIdx.x;
    if (i < KG_N) dinvk[i] = rsqrtf((float)(degi[i] + 1));   // +1 self loop
}

__global__ __launch_bounds__(1024) void scan_kernel(const int* __restrict__ degi,
                                                    int* __restrict__ ptr, int n) {
    __shared__ int buf[1024];
    __shared__ int carry;
    const int t = threadIdx.x;
    if (t == 0) { carry = 0; ptr[0] = 0; }
    __syncthreads();
    for (int base = 0; base < n; base += 1024) {
        const int i = base + t;
        int v = (i < n) ? degi[i] : 0;
        buf[t] = v;
        __syncthreads();
        for (int off = 1; off < 1024; off <<= 1) {
            int add = (t >= off) ? buf[t - off] : 0;
            __syncthreads();
            buf[t] += add;
            __syncthreads();
        }
        if (i < n) ptr[i + 1] = carry + buf[t];
        __syncthreads();
        if (t == 0) carry += buf[1023];
        __syncthreads();
    }
}

__global__ void kg_fill(const int* __restrict__ kg_ei, const int* __restrict__ ptr,
                        int* __restrict__ cursor, int* __restrict__ csr) {
    int e = blockIdx.x * 256 + threadIdx.x;
    if (e < E_KG) {
        int s = kg_ei[e];
        int d = kg_ei[E_KG + e];
        int pos = atomicAdd(&cursor[d], 1);
        csr[ptr[d] + pos] = s;
    }
}

__global__ __launch_bounds__(256) void kg_gemm1(const float* __restrict__ X,
                                                const float* __restrict__ W,
                                                const float* __restrict__ dinvk,
                                                float* __restrict__ Y) {
    __shared__ float es[4 * OUT_CH];
    const int t  = threadIdx.x;
    const int r0 = blockIdx.x * 4;
    if (t < 128) ((float4*)es)[t] = ((const float4*)(X + (size_t)r0 * OUT_CH))[t];
    __syncthreads();
    const int c = t;
    float a0 = 0.f, a1 = 0.f, a2 = 0.f, a3 = 0.f;
    for (int k = 0; k < OUT_CH; k += 4) {
        const float w0 = W[(k + 0) * HID + c], w1 = W[(k + 1) * HID + c],
                    w2 = W[(k + 2) * HID + c], w3 = W[(k + 3) * HID + c];
        float4 e0 = *(const float4*)&es[0 * OUT_CH + k];
        float4 e1 = *(const float4*)&es[1 * OUT_CH + k];
        float4 e2 = *(const float4*)&es[2 * OUT_CH + k];
        float4 e3 = *(const float4*)&es[3 * OUT_CH + k];
        a0 = fmaf(e0.x, w0, fmaf(e0.y, w1, fmaf(e0.z, w2, fmaf(e0.w, w3, a0))));
        a1 = fmaf(e1.x, w0, fmaf(e1.y, w1, fmaf(e1.z, w2, fmaf(e1.w, w3, a1))));
        a2 = fmaf(e2.x, w0, fmaf(e2.y, w1, fmaf(e2.z, w2, fmaf(e2.w, w3, a2))));
        a3 = fmaf(e3.x, w0, fmaf(e3.y, w1, fmaf(e3.z, w2, fmaf(e3.w, w3, a3))));
    }
    Y[(size_t)(r0 + 0) * HID + c] = dinvk[r0 + 0] * a0;
    Y[(size_t)(r0 + 1) * HID + c] = dinvk[r0 + 1] * a1;
    Y[(size_t)(r0 + 2) * HID + c] = dinvk[r0 + 2] * a2;
    Y[(size_t)(r0 + 3) * HID + c] = dinvk[r0 + 3] * a3;
}

__global__ __launch_bounds__(256) void kg_gemm2(const float* __restrict__ X,
                                                const float* __restrict__ W,
                                                const float* __restrict__ dinvk,
                                                float* __restrict__ Y) {
    __shared__ float es[8 * HID];
    const int t  = threadIdx.x;
    const int r0 = blockIdx.x * 8;
    {
        const float4* src = (const float4*)(X + (size_t)r0 * HID);
        float4* dst = (float4*)es;
        dst[t]       = src[t];
        dst[t + 256] = src[t + 256];
    }
    __syncthreads();
    const int c   = t & 127;
    const int rr0 = (t >> 7) * 4;
    float acc[4] = {0.f, 0.f, 0.f, 0.f};
    for (int k = 0; k < HID; k += 4) {
        const float w0 = W[(k + 0) * OUT_CH + c], w1 = W[(k + 1) * OUT_CH + c],
                    w2 = W[(k + 2) * OUT_CH + c], w3 = W[(k + 3) * OUT_CH + c];
        #pragma unroll
        for (int r = 0; r < 4; ++r) {
            float4 e = *(const float4*)&es[(rr0 + r) * HID + k];
            acc[r] = fmaf(e.x, w0, fmaf(e.y, w1, fmaf(e.z, w2, fmaf(e.w, w3, acc[r]))));
        }
    }
    #pragma unroll
    for (int r = 0; r < 4; ++r)
        Y[(size_t)(r0 + rr0 + r) * OUT_CH + c] = dinvk[r0 + rr0 + r] * acc[r];
}

template <int C, bool RELU>
__global__ __launch_bounds__(C) void kg_agg_kernel(
    const float* __restrict__ xw, const float* __restrict__ dinvk,
    const int* __restrict__ ptr, const int* __restrict__ csr,
    const float* __restrict__ bias, float* __restrict__ out)
{
    const int n = blockIdx.x;
    const int c = threadIdx.x;
    const int e1 = ptr[n + 1];
    int e = ptr[n];
    float acc = xw[(size_t)n * C + c];
    int sn = (e < e1) ? csr[e] : 0;
    while (e < e1) {
        const int s = sn;
        ++e;
        sn = (e < e1) ? csr[e] : 0;
        acc += xw[(size_t)s * C + c];
    }
    float v = fmaf(dinvk[n], acc, bias[c]);
    if (RELU) v = v > 0.f ? v : 0.f;
    out[(size_t)n * C + c] = v;
}

// ---------------------------------------------------------------------------
extern "C" void kernel_launch(void* const* d_in, const int* in_sizes, int n_in,
                              void* d_out, int out_size, void* d_ws, size_t ws_size,
                              hipStream_t stream) {
    const float* mol_x  = (const float*)d_in[0];
    const int*   mol_ei = (const int*)  d_in[1];
    const int*   kg_ei  = (const int*)  d_in[2];
    const float* W1 = (const float*)d_in[3];  const float* b1 = (const float*)d_in[4];
    const float* W2 = (const float*)d_in[5];  const float* b2 = (const float*)d_in[6];
    const float* W3 = (const float*)d_in[7];  const float* b3 = (const float*)d_in[8];
    const float* Wk1 = (const float*)d_in[9];  const float* bk1 = (const float*)d_in[10];
    const float* Wk2 = (const float*)d_in[11]; const float* bk2 = (const float*)d_in[12];
    float* out = (float*)d_out;

    char* ws = (char*)d_ws;
    size_t off = 0;
    auto alloc = [&](size_t bytes) -> void* {
        void* p = ws + off;
        off += (bytes + 255) & ~(size_t)255;
        return p;
    };
    float* embed = (float*)alloc((size_t)M_MOLS * OUT_CH * 4);
    float* xw1   = (float*)alloc((size_t)KG_N * HID * 4);
    float* h1    = (float*)alloc((size_t)KG_N * HID * 4);
    float* xw2   = (float*)alloc((size_t)KG_N * OUT_CH * 4);
    int*   degi  = (int*)  alloc((size_t)KG_N * 4);
    float* dinvk = (float*)alloc((size_t)KG_N * 4);
    int*   ptr   = (int*)  alloc((size_t)(KG_N + 4) * 4);
    int*   cursor= (int*)  alloc((size_t)KG_N * 4);
    int*   csr   = (int*)  alloc((size_t)E_KG * 4);
    short* wt1   = (short*)alloc((size_t)IN_CH * HID * 2);     // [256][64]
    short* wt2   = (short*)alloc((size_t)HID * HID * 2);       // [256][256]
    short* wt3   = (short*)alloc((size_t)OUT_CH * HID * 2);    // [128][256]

    hipMemsetAsync(degi,   0, (size_t)KG_N * 4, stream);
    hipMemsetAsync(cursor, 0, (size_t)KG_N * 4, stream);

    // Weight prep (bf16, transposed)
    prep_wt<<<(IN_CH * HID + 255) / 256, 256, 0, stream>>>(W1, wt1, IN_CH, HID, IN_CH * HID);
    prep_wt<<<(HID * HID + 255) / 256, 256, 0, stream>>>(W2, wt2, HID, HID, HID * HID);
    prep_wt<<<(OUT_CH * HID + 255) / 256, 256, 0, stream>>>(W3, wt3, HID, OUT_CH, HID * OUT_CH);

    // Phase A: molecule GNN -> embed [10000, 128]
    mol_kernel<<<M_MOLS, 256, 0, stream>>>(mol_x, mol_ei, wt1, b1, wt2, b2, wt3, b3, embed);

    // Phase B: CSR build for KG graph
    kg_count<<<(E_KG + 255) / 256, 256, 0, stream>>>(kg_ei, degi);
    scan_kernel<<<1, 1024, 0, stream>>>(degi, ptr, KG_N);
    kg_dinv<<<(KG_N + 255) / 256, 256, 0, stream>>>(degi, dinvk);
    kg_fill<<<(E_KG + 255) / 256, 256, 0, stream>>>(kg_ei, ptr, cursor, csr);

    // KG layer 1: relu(gcn(embed, Wk1) + bk1)
    kg_gemm1<<<KG_N / 4, 256, 0, stream>>>(embed, Wk1, dinvk, xw1);
    kg_agg_kernel<HID, true><<<KG_N, HID, 0, stream>>>(xw1, dinvk, ptr, csr, bk1, h1);

    // KG layer 2: gcn(h1, Wk2) + bk2 -> out
    kg_gemm2<<<KG_N / 8, 256, 0, stream>>>(h1, Wk2, dinvk, xw2);
    kg_agg_kernel<OUT_CH, false><<<KG_N, OUT_CH, 0, stream>>>(xw2, dinvk, ptr, csr, bk2, out);
}

// Round 3
// 612.595 us; speedup vs baseline: 3.4436x; 1.3944x over previous
//
#include <hip/hip_runtime.h>

#define M_MOLS  10000
#define NA      32     // atoms per molecule
#define E_MOL   64
#define IN_CH   64
#define OUT_CH  128
#define HID     256
#define E_KG    320000
#define KG_N    10000

typedef __attribute__((ext_vector_type(8))) short  s16x8;  // 8 bf16 (4 VGPR)
typedef __attribute__((ext_vector_type(4))) short  s16x4;  // 4 bf16 (8B)
typedef __attribute__((ext_vector_type(4))) float  f32x4;

// RNE float -> bf16 bits (finite inputs only)
static __device__ __forceinline__ short f2bf(float f) {
    unsigned u = __float_as_uint(f);
    u += 0x7FFFu + ((u >> 16) & 1u);
    return (short)(u >> 16);
}

// ---------------------------------------------------------------------------
// Weight prep: WT[c][k] = bf16(W[k][c])
// ---------------------------------------------------------------------------
__global__ void prep_wt(const float* __restrict__ W, short* __restrict__ WT,
                        int K, int C, int total) {
    int idx = blockIdx.x * 256 + threadIdx.x;
    if (idx < total) {
        int c = idx / K, k = idx - c * K;
        WT[idx] = f2bf(W[k * C + c]);
    }
}

// ---------------------------------------------------------------------------
// Molecule GNN, all-MFMA, no AT round-trip.
// Wave owns NCT col-tiles across BOTH 16-row atom groups. GEMM acc ->
// (in-register shfl transpose) -> agg A-op; agg computed as Hnext^T = A^T@B
// so Hs writes are packed 8B. LDS 26.4KB -> 6 blocks/CU.
// Hs layout: [32][256] bf16, XOR-swizzled byte ^= (row&7)<<4.
// BT[i][s] = bf16(Bm[s][i]), rows padded to 40 shorts (80B).
// ---------------------------------------------------------------------------
__global__ __launch_bounds__(256, 6) void mol_kernel(
    const float* __restrict__ mol_x, const int* __restrict__ mol_ei,
    const short* __restrict__ WT1, const float* __restrict__ b1,
    const short* __restrict__ WT2, const float* __restrict__ b2,
    const short* __restrict__ WT3, const float* __restrict__ b3,
    float* __restrict__ embed)
{
    __shared__ short Hs[NA * HID];               // 16 KB
    __shared__ short BT[NA * 40];                // 2.5 KB
    __shared__ float Bm[NA * NA];                // 4 KB (reused as min-pool buf)
    __shared__ float bias_s[2 * HID + OUT_CH];   // 2.56 KB
    __shared__ int   se[E_MOL], de[E_MOL];
    __shared__ float dinv[NA];
    __shared__ int   deg[NA];

    const int t    = threadIdx.x;
    const int mol  = blockIdx.x;
    const int lane = t & 63;
    const int wid  = t >> 6;
    const int lr   = lane & 15;
    const int lk   = lane >> 4;
    char* HsB = (char*)Hs;

    // ---- stage x -> Hs bf16 (rows 0..31, k 0..63), swizzled 16B writes ----
    {
        const float4* src = (const float4*)(mol_x + (size_t)mol * (NA * IN_CH));
        float4 a = src[t * 2], b = src[t * 2 + 1];
        s16x8 v;
        v[0] = f2bf(a.x); v[1] = f2bf(a.y); v[2] = f2bf(a.z); v[3] = f2bf(a.w);
        v[4] = f2bf(b.x); v[5] = f2bf(b.y); v[6] = f2bf(b.z); v[7] = f2bf(b.w);
        int row = t >> 3, k0 = (t & 7) * 8;
        int byte = (row << 9) + (k0 << 1); byte ^= (row & 7) << 4;
        *(s16x8*)(HsB + byte) = v;
    }
    // ---- edges, degrees, normalized adjacency ----
    {
        const int* eb = mol_ei + (size_t)mol * (2 * E_MOL);
        if (t < E_MOL)            se[t]         = eb[t];
        else if (t < 2 * E_MOL)   de[t - E_MOL] = eb[t];
    }
    if (t < NA) deg[t] = 1;                       // self loop
    for (int i = t; i < NA * NA; i += 256) Bm[i] = 0.f;
    for (int i = t; i < 2 * HID + OUT_CH; i += 256)
        bias_s[i] = (i < HID) ? b1[i] : (i < 2 * HID) ? b2[i - HID] : b3[i - 2 * HID];
    __syncthreads();
    if (t < E_MOL) atomicAdd(&deg[de[t]], 1);
    __syncthreads();
    if (t < NA) dinv[t] = rsqrtf((float)deg[t]);
    __syncthreads();
    if (t < E_MOL) {
        atomicAdd(&Bm[se[t] * NA + de[t]], dinv[se[t]] * dinv[de[t]]);
    } else if (t < E_MOL + NA) {
        int i = t - E_MOL;
        atomicAdd(&Bm[i * NA + i], dinv[i] * dinv[i]);
    }
    __syncthreads();
    for (int i = t; i < NA * NA; i += 256) {      // BT[i][s] = Bm[s][i]
        int r = i >> 5, s = i & 31;
        BT[r * 40 + s] = f2bf(Bm[s * NA + r]);
    }
    __syncthreads();   // Hs(x), BT, bias all valid

    const f32x4 z4 = {0.f, 0.f, 0.f, 0.f};

    // GEMM: acc[it][c] = tile(atoms it*16.., cols (ct0+c)*16..) of Hs @ W
#define GEMM_PHASE(WT, K, NCT, CT0)                                            \
    _Pragma("unroll")                                                          \
    for (int it = 0; it < 2; ++it)                                             \
        _Pragma("unroll")                                                      \
        for (int c = 0; c < NCT; ++c) acc[it][c] = z4;                         \
    for (int ks = 0; ks < (K) / 32; ++ks) {                                    \
        s16x8 af[2];                                                           \
        _Pragma("unroll")                                                      \
        for (int it = 0; it < 2; ++it) {                                       \
            int row = it * 16 + lr;                                            \
            int byte = (row << 9) + ((ks * 32 + lk * 8) << 1);                 \
            byte ^= (row & 7) << 4;                                            \
            af[it] = *(const s16x8*)(HsB + byte);                              \
        }                                                                      \
        _Pragma("unroll")                                                      \
        for (int c = 0; c < NCT; ++c) {                                        \
            s16x8 bf = *(const s16x8*)((WT) +                                  \
                (size_t)(((CT0) + c) * 16 + lr) * (K) + ks * 32 + lk * 8);     \
            acc[0][c] = __builtin_amdgcn_mfma_f32_16x16x32_bf16(af[0], bf,     \
                                                               acc[0][c], 0, 0, 0); \
            acc[1][c] = __builtin_amdgcn_mfma_f32_16x16x32_bf16(af[1], bf,     \
                                                               acc[1][c], 0, 0, 0); \
        }                                                                      \
    }

    // transpose acc[*][c] -> atf: lane(lk,lr) = A^T[col=(ct)*16+lr][s=lk*8+m]
#define TRANSPOSE(cIdx, atf)                                                   \
    {                                                                          \
        float vals[8];                                                         \
        _Pragma("unroll")                                                      \
        for (int m = 0; m < 8; ++m) {                                          \
            int src = ((((lk & 1) << 1) + (m >> 2)) << 4) + lr;                \
            float v0 = __shfl(acc[0][cIdx][m & 3], src);                       \
            float v1 = __shfl(acc[1][cIdx][m & 3], src);                       \
            vals[m] = (lk & 2) ? v1 : v0;                                      \
        }                                                                      \
        _Pragma("unroll")                                                      \
        for (int m = 0; m < 8; ++m) atf[m] = f2bf(vals[m]);                    \
    }

    // AGG (layers 1,2): Hnext^T tile = atf @ btf; packed 8B Hs writes
#define AGG_PHASE(NCT, CT0, BOFF, RELU)                                        \
    _Pragma("unroll")                                                          \
    for (int c = 0; c < NCT; ++c) {                                            \
        s16x8 atf;                                                             \
        TRANSPOSE(c, atf)                                                      \
        _Pragma("unroll")                                                      \
        for (int itn = 0; itn < 2; ++itn) {                                    \
            s16x8 btf = *(const s16x8*)(BT + (itn * 16 + lr) * 40 + lk * 8);   \
            f32x4 g = __builtin_amdgcn_mfma_f32_16x16x32_bf16(atf, btf, z4,    \
                                                              0, 0, 0);        \
            int c0 = ((CT0) + c) * 16 + lk * 4;                                \
            s16x4 w;                                                           \
            _Pragma("unroll")                                                  \
            for (int jj = 0; jj < 4; ++jj) {                                   \
                float v = g[jj] + bias_s[(BOFF) + c0 + jj];                    \
                if (RELU) v = v > 0.f ? v : 0.f;                               \
                w[jj] = f2bf(v);                                               \
            }                                                                  \
            int row = itn * 16 + lr;                                           \
            int byte = (row << 9) + (c0 << 1); byte ^= (row & 7) << 4;         \
            *(s16x4*)(HsB + byte) = w;                                         \
        }                                                                      \
    }

    const int ct0 = wid * 4;       // layers 1,2: 4 col-tiles/wave
    const int ct3 = wid * 2;       // layer 3:    2 col-tiles/wave
    {   // ---- layer 1 ----
        f32x4 acc[2][4];
        GEMM_PHASE(WT1, IN_CH, 4, ct0)
        __syncthreads();                       // all Hs(x) reads done
        AGG_PHASE(4, ct0, 0, true)
        __syncthreads();                       // Hs(h1) visible
    }
    {   // ---- layer 2 ----
        f32x4 acc[2][4];
        GEMM_PHASE(WT2, HID, 4, ct0)
        __syncthreads();
        AGG_PHASE(4, ct0, HID, true)
        __syncthreads();
    }
    {   // ---- layer 3 + min-pool (no Hs write) ----
        f32x4 acc[2][2];
        GEMM_PHASE(WT3, HID, 2, ct3)
        __syncthreads();                       // Hs reads done (Bm reuse safe)
        #pragma unroll
        for (int c = 0; c < 2; ++c) {
            s16x8 atf;
            TRANSPOSE(c, atf)
            float mn[4] = {1e30f, 1e30f, 1e30f, 1e30f};
            #pragma unroll
            for (int itn = 0; itn < 2; ++itn) {
                s16x8 btf = *(const s16x8*)(BT + (itn * 16 + lr) * 40 + lk * 8);
                f32x4 g = __builtin_amdgcn_mfma_f32_16x16x32_bf16(atf, btf, z4,
                                                                  0, 0, 0);
                #pragma unroll
                for (int jj = 0; jj < 4; ++jj) mn[jj] = fminf(mn[jj], g[jj]);
            }
            #pragma unroll
            for (int off = 1; off < 16; off <<= 1) {
                #pragma unroll
                for (int jj = 0; jj < 4; ++jj)
                    mn[jj] = fminf(mn[jj], __shfl_xor(mn[jj], off));
            }
            if (lr == 0) {
                int c0 = (ct3 + c) * 16 + lk * 4;
                #pragma unroll
                for (int jj = 0; jj < 4; ++jj)
                    Bm[c0 + jj] = mn[jj] + bias_s[2 * HID + c0 + jj];
            }
        }
    }
    __syncthreads();
    if (t < OUT_CH) embed[(size_t)mol * OUT_CH + t] = Bm[t];
#undef GEMM_PHASE
#undef TRANSPOSE
#undef AGG_PHASE
}

// ---------------------------------------------------------------------------
// KG graph: CSR build, fp32 GEMMs, float4 gather-aggregate.
// ---------------------------------------------------------------------------
__global__ void kg_count(const int* __restrict__ kg_ei, int* __restrict__ degi) {
    int e = blockIdx.x * 256 + threadIdx.x;
    if (e < E_KG) atomicAdd(&degi[kg_ei[E_KG + e]], 1);
}

__global__ void kg_dinv(const int* __restrict__ degi, float* __restrict__ dinvk) {
    int i = blockIdx.x * 256 + threadIdx.x;
    if (i < KG_N) dinvk[i] = rsqrtf((float)(degi[i] + 1));   // +1 self loop
}

// single-block scan, register-blocked: 1024 thr x 10 elems, 2 barriers
__global__ __launch_bounds__(1024) void scan_kernel(const int* __restrict__ degi,
                                                    int* __restrict__ ptr, int n) {
    __shared__ int wsum[16];
    const int t = threadIdx.x;
    const int base = t * 10;
    int inc[10];
    int s = 0;
    #pragma unroll
    for (int i = 0; i < 10; ++i) {
        int idx = base + i;
        s += (idx < n) ? degi[idx] : 0;
        inc[i] = s;
    }
    const int lane = t & 63;
    int ps = s;
    #pragma unroll
    for (int off = 1; off < 64; off <<= 1) {
        int u = __shfl_up(ps, off);
        if (lane >= off) ps += u;
    }
    if (lane == 63) wsum[t >> 6] = ps;
    __syncthreads();
    if (t == 0) {
        int run = 0;
        #pragma unroll
        for (int k = 0; k < 16; ++k) { int x = wsum[k]; wsum[k] = run; run += x; }
        ptr[0] = 0;
    }
    __syncthreads();
    const int excl = wsum[t >> 6] + (ps - s);
    #pragma unroll
    for (int i = 0; i < 10; ++i) {
        int idx = base + i;
        if (idx < n) ptr[idx + 1] = excl + inc[i];
    }
}

__global__ void kg_fill(const int* __restrict__ kg_ei, const int* __restrict__ ptr,
                        int* __restrict__ cursor, int* __restrict__ csr) {
    int e = blockIdx.x * 256 + threadIdx.x;
    if (e < E_KG) {
        int s = kg_ei[e];
        int d = kg_ei[E_KG + e];
        int pos = atomicAdd(&cursor[d], 1);
        csr[ptr[d] + pos] = s;
    }
}

__global__ __launch_bounds__(256) void kg_gemm1(const float* __restrict__ X,
                                                const float* __restrict__ W,
                                                const float* __restrict__ dinvk,
                                                float* __restrict__ Y) {
    __shared__ float es[4 * OUT_CH];
    const int t  = threadIdx.x;
    const int r0 = blockIdx.x * 4;
    if (t < 128) ((float4*)es)[t] = ((const float4*)(X + (size_t)r0 * OUT_CH))[t];
    __syncthreads();
    const int c = t;
    float a0 = 0.f, a1 = 0.f, a2 = 0.f, a3 = 0.f;
    for (int k = 0; k < OUT_CH; k += 4) {
        const float w0 = W[(k + 0) * HID + c], w1 = W[(k + 1) * HID + c],
                    w2 = W[(k + 2) * HID + c], w3 = W[(k + 3) * HID + c];
        float4 e0 = *(const float4*)&es[0 * OUT_CH + k];
        float4 e1 = *(const float4*)&es[1 * OUT_CH + k];
        float4 e2 = *(const float4*)&es[2 * OUT_CH + k];
        float4 e3 = *(const float4*)&es[3 * OUT_CH + k];
        a0 = fmaf(e0.x, w0, fmaf(e0.y, w1, fmaf(e0.z, w2, fmaf(e0.w, w3, a0))));
        a1 = fmaf(e1.x, w0, fmaf(e1.y, w1, fmaf(e1.z, w2, fmaf(e1.w, w3, a1))));
        a2 = fmaf(e2.x, w0, fmaf(e2.y, w1, fmaf(e2.z, w2, fmaf(e2.w, w3, a2))));
        a3 = fmaf(e3.x, w0, fmaf(e3.y, w1, fmaf(e3.z, w2, fmaf(e3.w, w3, a3))));
    }
    Y[(size_t)(r0 + 0) * HID + c] = dinvk[r0 + 0] * a0;
    Y[(size_t)(r0 + 1) * HID + c] = dinvk[r0 + 1] * a1;
    Y[(size_t)(r0 + 2) * HID + c] = dinvk[r0 + 2] * a2;
    Y[(size_t)(r0 + 3) * HID + c] = dinvk[r0 + 3] * a3;
}

__global__ __launch_bounds__(256) void kg_gemm2(const float* __restrict__ X,
                                                const float* __restrict__ W,
                                                const float* __restrict__ dinvk,
                                                float* __restrict__ Y) {
    __shared__ float es[8 * HID];
    const int t  = threadIdx.x;
    const int r0 = blockIdx.x * 8;
    {
        const float4* src = (const float4*)(X + (size_t)r0 * HID);
        float4* dst = (float4*)es;
        dst[t]       = src[t];
        dst[t + 256] = src[t + 256];
    }
    __syncthreads();
    const int c   = t & 127;
    const int rr0 = (t >> 7) * 4;
    float acc[4] = {0.f, 0.f, 0.f, 0.f};
    for (int k = 0; k < HID; k += 4) {
        const float w0 = W[(k + 0) * OUT_CH + c], w1 = W[(k + 1) * OUT_CH + c],
                    w2 = W[(k + 2) * OUT_CH + c], w3 = W[(k + 3) * OUT_CH + c];
        #pragma unroll
        for (int r = 0; r < 4; ++r) {
            float4 e = *(const float4*)&es[(rr0 + r) * HID + k];
            acc[r] = fmaf(e.x, w0, fmaf(e.y, w1, fmaf(e.z, w2, fmaf(e.w, w3, acc[r]))));
        }
    }
    #pragma unroll
    for (int r = 0; r < 4; ++r)
        Y[(size_t)(r0 + rr0 + r) * OUT_CH + c] = dinvk[r0 + rr0 + r] * acc[r];
}

// float4-per-lane gather aggregate; 64-thread blocks, NPB nodes per block
template <int C, bool RELU>
__global__ __launch_bounds__(64) void kg_agg_kernel(
    const float* __restrict__ xw, const float* __restrict__ dinvk,
    const int* __restrict__ ptr, const int* __restrict__ csr,
    const float* __restrict__ bias, float* __restrict__ out)
{
    constexpr int C4  = C / 4;
    constexpr int NPB = 64 / C4;
    const int sub = threadIdx.x / C4;
    const int t   = threadIdx.x - sub * C4;
    const int n   = blockIdx.x * NPB + sub;
    const float4* xw4 = (const float4*)xw;
    const int e1 = ptr[n + 1];
    float4 acc = xw4[(size_t)n * C4 + t];
    for (int e = ptr[n]; e < e1; ++e) {
        int s = csr[e];
        float4 v = xw4[(size_t)s * C4 + t];
        acc.x += v.x; acc.y += v.y; acc.z += v.z; acc.w += v.w;
    }
    const float dn = dinvk[n];
    const float4 b = ((const float4*)bias)[t];
    float4 o;
    o.x = fmaf(dn, acc.x, b.x); o.y = fmaf(dn, acc.y, b.y);
    o.z = fmaf(dn, acc.z, b.z); o.w = fmaf(dn, acc.w, b.w);
    if (RELU) {
        o.x = o.x > 0.f ? o.x : 0.f; o.y = o.y > 0.f ? o.y : 0.f;
        o.z = o.z > 0.f ? o.z : 0.f; o.w = o.w > 0.f ? o.w : 0.f;
    }
    ((float4*)out)[(size_t)n * C4 + t] = o;
}

// ---------------------------------------------------------------------------
extern "C" void kernel_launch(void* const* d_in, const int* in_sizes, int n_in,
                              void* d_out, int out_size, void* d_ws, size_t ws_size,
                              hipStream_t stream) {
    const float* mol_x  = (const float*)d_in[0];
    const int*   mol_ei = (const int*)  d_in[1];
    const int*   kg_ei  = (const int*)  d_in[2];
    const float* W1 = (const float*)d_in[3];  const float* b1 = (const float*)d_in[4];
    const float* W2 = (const float*)d_in[5];  const float* b2 = (const float*)d_in[6];
    const float* W3 = (const float*)d_in[7];  const float* b3 = (const float*)d_in[8];
    const float* Wk1 = (const float*)d_in[9];  const float* bk1 = (const float*)d_in[10];
    const float* Wk2 = (const float*)d_in[11]; const float* bk2 = (const float*)d_in[12];
    float* out = (float*)d_out;

    char* ws = (char*)d_ws;
    size_t off = 0;
    auto alloc = [&](size_t bytes) -> void* {
        void* p = ws + off;
        off += (bytes + 255) & ~(size_t)255;
        return p;
    };
    float* embed = (float*)alloc((size_t)M_MOLS * OUT_CH * 4);
    float* xw1   = (float*)alloc((size_t)KG_N * HID * 4);
    float* h1    = (float*)alloc((size_t)KG_N * HID * 4);
    float* xw2   = (float*)alloc((size_t)KG_N * OUT_CH * 4);
    int*   degi  = (int*)  alloc((size_t)KG_N * 4);
    float* dinvk = (float*)alloc((size_t)KG_N * 4);
    int*   ptr   = (int*)  alloc((size_t)(KG_N + 4) * 4);
    int*   cursor= (int*)  alloc((size_t)KG_N * 4);
    int*   csr   = (int*)  alloc((size_t)E_KG * 4);
    short* wt1   = (short*)alloc((size_t)IN_CH * HID * 2);     // [256][64]
    short* wt2   = (short*)alloc((size_t)HID * HID * 2);       // [256][256]
    short* wt3   = (short*)alloc((size_t)OUT_CH * HID * 2);    // [128][256]

    hipMemsetAsync(degi,   0, (size_t)KG_N * 4, stream);
    hipMemsetAsync(cursor, 0, (size_t)KG_N * 4, stream);

    prep_wt<<<(IN_CH * HID + 255) / 256, 256, 0, stream>>>(W1, wt1, IN_CH, HID, IN_CH * HID);
    prep_wt<<<(HID * HID + 255) / 256, 256, 0, stream>>>(W2, wt2, HID, HID, HID * HID);
    prep_wt<<<(OUT_CH * HID + 255) / 256, 256, 0, stream>>>(W3, wt3, HID, OUT_CH, HID * OUT_CH);

    // Phase A: molecule GNN -> embed [10000, 128]
    mol_kernel<<<M_MOLS, 256, 0, stream>>>(mol_x, mol_ei, wt1, b1, wt2, b2, wt3, b3, embed);

    // Phase B: CSR build for KG graph
    kg_count<<<(E_KG + 255) / 256, 256, 0, stream>>>(kg_ei, degi);
    scan_kernel<<<1, 1024, 0, stream>>>(degi, ptr, KG_N);
    kg_dinv<<<(KG_N + 255) / 256, 256, 0, stream>>>(degi, dinvk);
    kg_fill<<<(E_KG + 255) / 256, 256, 0, stream>>>(kg_ei, ptr, cursor, csr);

    // KG layer 1: relu(gcn(embed, Wk1) + bk1)
    kg_gemm1<<<KG_N / 4, 256, 0, stream>>>(embed, Wk1, dinvk, xw1);
    kg_agg_kernel<HID, true><<<KG_N, 64, 0, stream>>>(xw1, dinvk, ptr, csr, bk1, h1);

    // KG layer 2: gcn(h1, Wk2) + bk2 -> out
    kg_gemm2<<<KG_N / 8, 256, 0, stream>>>(h1, Wk2, dinvk, xw2);
    kg_agg_kernel<OUT_CH, false><<<KG_N / 2, 64, 0, stream>>>(xw2, dinvk, ptr, csr, bk2, out);
}

// Round 4
// 555.187 us; speedup vs baseline: 3.7997x; 1.1034x over previous
//
#include <hip/hip_runtime.h>

#define M_MOLS  10000
#define NA      32     // atoms per molecule
#define E_MOL   64
#define IN_CH   64
#define OUT_CH  128
#define HID     256
#define E_KG    320000
#define KG_N    10000

typedef __attribute__((ext_vector_type(8))) short  s16x8;  // 8 bf16 (4 VGPR)
typedef __attribute__((ext_vector_type(4))) short  s16x4;  // 4 bf16 (8B)
typedef __attribute__((ext_vector_type(4))) float  f32x4;

// RNE float -> bf16 bits (finite inputs only)
static __device__ __forceinline__ short f2bf(float f) {
    unsigned u = __float_as_uint(f);
    u += 0x7FFFu + ((u >> 16) & 1u);
    return (short)(u >> 16);
}

// ---------------------------------------------------------------------------
// Weight prep: WT[c][k] = bf16(W[k][c])
// ---------------------------------------------------------------------------
__global__ void prep_wt(const float* __restrict__ W, short* __restrict__ WT,
                        int K, int C, int total) {
    int idx = blockIdx.x * 256 + threadIdx.x;
    if (idx < total) {
        int c = idx / K, k = idx - c * K;
        WT[idx] = f2bf(W[k * C + c]);
    }
}

// ---------------------------------------------------------------------------
// Molecule GNN, all-MFMA, no AT round-trip, no spills.
// __launch_bounds__(256,4): VGPR cap 128 (acc needs 32 + operands ~50) —
// (256,6) capped at 85 and spilled 399MB/dispatch to scratch (round 3).
// BmT[dst][src] built directly so the bf16 transpose-copy reads LDS rows
// linearly (round 3 read 128B-stride columns: 32-way bank conflict).
// Hs layout: [32][256] bf16, XOR-swizzled byte ^= (row&7)<<4.
// Epilogue: embed prescaled by dinvk (KG-side D^-1/2), folding a KG pass.
// ---------------------------------------------------------------------------
__global__ __launch_bounds__(256, 4) void mol_kernel(
    const float* __restrict__ mol_x, const int* __restrict__ mol_ei,
    const short* __restrict__ WT1, const float* __restrict__ b1,
    const short* __restrict__ WT2, const float* __restrict__ b2,
    const short* __restrict__ WT3, const float* __restrict__ b3,
    const float* __restrict__ dinvk, float* __restrict__ embed)
{
    __shared__ short Hs[NA * HID];               // 16 KB
    __shared__ short BT[NA * 40];                // 2.5 KB  BT[i][s] bf16, 80B rows
    __shared__ float BmT[NA * NA];               // 4 KB    BmT[dst][src] fp32
    __shared__ float bias_s[2 * HID + OUT_CH];   // 2.56 KB
    __shared__ int   se[E_MOL], de[E_MOL];
    __shared__ float dinv[NA];
    __shared__ int   deg[NA];

    const int t    = threadIdx.x;
    const int mol  = blockIdx.x;
    const int lane = t & 63;
    const int wid  = t >> 6;
    const int lr   = lane & 15;
    const int lk   = lane >> 4;
    char* HsB = (char*)Hs;

    // ---- stage x -> Hs bf16 (rows 0..31, k 0..63), swizzled 16B writes ----
    {
        const float4* src = (const float4*)(mol_x + (size_t)mol * (NA * IN_CH));
        float4 a = src[t * 2], b = src[t * 2 + 1];
        s16x8 v;
        v[0] = f2bf(a.x); v[1] = f2bf(a.y); v[2] = f2bf(a.z); v[3] = f2bf(a.w);
        v[4] = f2bf(b.x); v[5] = f2bf(b.y); v[6] = f2bf(b.z); v[7] = f2bf(b.w);
        int row = t >> 3, k0 = (t & 7) * 8;
        int byte = (row << 9) + (k0 << 1); byte ^= (row & 7) << 4;
        *(s16x8*)(HsB + byte) = v;
    }
    // ---- edges, degrees, normalized adjacency (built transposed) ----
    {
        const int* eb = mol_ei + (size_t)mol * (2 * E_MOL);
        if (t < E_MOL)            se[t]         = eb[t];
        else if (t < 2 * E_MOL)   de[t - E_MOL] = eb[t];
    }
    if (t < NA) deg[t] = 1;                       // self loop
    for (int i = t; i < NA * NA; i += 256) BmT[i] = 0.f;
    for (int i = t; i < 2 * HID + OUT_CH; i += 256)
        bias_s[i] = (i < HID) ? b1[i] : (i < 2 * HID) ? b2[i - HID] : b3[i - 2 * HID];
    __syncthreads();
    if (t < E_MOL) atomicAdd(&deg[de[t]], 1);
    __syncthreads();
    if (t < NA) dinv[t] = rsqrtf((float)deg[t]);
    __syncthreads();
    if (t < E_MOL) {
        // BmT[dst][src] = norm(src->dst)
        atomicAdd(&BmT[de[t] * NA + se[t]], dinv[se[t]] * dinv[de[t]]);
    } else if (t < E_MOL + NA) {
        int i = t - E_MOL;
        atomicAdd(&BmT[i * NA + i], dinv[i] * dinv[i]);
    }
    __syncthreads();
    for (int i = t; i < NA * NA; i += 256)        // linear row copy, no conflict
        BT[(i >> 5) * 40 + (i & 31)] = f2bf(BmT[i]);
    __syncthreads();   // Hs(x), BT, bias all valid

    const f32x4 z4 = {0.f, 0.f, 0.f, 0.f};

    // GEMM: acc[it][c] = tile(atoms it*16.., cols (ct0+c)*16..) of Hs @ W
#define GEMM_PHASE(WT, K, NCT, CT0)                                            \
    _Pragma("unroll")                                                          \
    for (int it = 0; it < 2; ++it)                                             \
        _Pragma("unroll")                                                      \
        for (int c = 0; c < NCT; ++c) acc[it][c] = z4;                         \
    for (int ks = 0; ks < (K) / 32; ++ks) {                                    \
        s16x8 af[2];                                                           \
        _Pragma("unroll")                                                      \
        for (int it = 0; it < 2; ++it) {                                       \
            int row = it * 16 + lr;                                            \
            int byte = (row << 9) + ((ks * 32 + lk * 8) << 1);                 \
            byte ^= (row & 7) << 4;                                            \
            af[it] = *(const s16x8*)(HsB + byte);                              \
        }                                                                      \
        _Pragma("unroll")                                                      \
        for (int c = 0; c < NCT; ++c) {                                        \
            s16x8 bf = *(const s16x8*)((WT) +                                  \
                (size_t)(((CT0) + c) * 16 + lr) * (K) + ks * 32 + lk * 8);     \
            acc[0][c] = __builtin_amdgcn_mfma_f32_16x16x32_bf16(af[0], bf,     \
                                                               acc[0][c], 0, 0, 0); \
            acc[1][c] = __builtin_amdgcn_mfma_f32_16x16x32_bf16(af[1], bf,     \
                                                               acc[1][c], 0, 0, 0); \
        }                                                                      \
    }

    // transpose acc[*][c] -> atf: lane(lk,lr) = A^T[col=(ct)*16+lr][s=lk*8+m]
#define TRANSPOSE(cIdx, atf)                                                   \
    {                                                                          \
        float vals[8];                                                         \
        _Pragma("unroll")                                                      \
        for (int m = 0; m < 8; ++m) {                                          \
            int src = ((((lk & 1) << 1) + (m >> 2)) << 4) + lr;                \
            float v0 = __shfl(acc[0][cIdx][m & 3], src);                       \
            float v1 = __shfl(acc[1][cIdx][m & 3], src);                       \
            vals[m] = (lk & 2) ? v1 : v0;                                      \
        }                                                                      \
        _Pragma("unroll")                                                      \
        for (int m = 0; m < 8; ++m) atf[m] = f2bf(vals[m]);                    \
    }

    // AGG (layers 1,2): Hnext^T tile = atf @ btf; packed 8B Hs writes
#define AGG_PHASE(NCT, CT0, BOFF, RELU)                                        \
    _Pragma("unroll")                                                          \
    for (int c = 0; c < NCT; ++c) {                                            \
        s16x8 atf;                                                             \
        TRANSPOSE(c, atf)                                                      \
        _Pragma("unroll")                                                      \
        for (int itn = 0; itn < 2; ++itn) {                                    \
            s16x8 btf = *(const s16x8*)(BT + (itn * 16 + lr) * 40 + lk * 8);   \
            f32x4 g = __builtin_amdgcn_mfma_f32_16x16x32_bf16(atf, btf, z4,    \
                                                              0, 0, 0);        \
            int c0 = ((CT0) + c) * 16 + lk * 4;                                \
            s16x4 w;                                                           \
            _Pragma("unroll")                                                  \
            for (int jj = 0; jj < 4; ++jj) {                                   \
                float v = g[jj] + bias_s[(BOFF) + c0 + jj];                    \
                if (RELU) v = v > 0.f ? v : 0.f;                               \
                w[jj] = f2bf(v);                                               \
            }                                                                  \
            int row = itn * 16 + lr;                                           \
            int byte = (row << 9) + (c0 << 1); byte ^= (row & 7) << 4;         \
            *(s16x4*)(HsB + byte) = w;                                         \
        }                                                                      \
    }

    const int ct0 = wid * 4;       // layers 1,2: 4 col-tiles/wave
    const int ct3 = wid * 2;       // layer 3:    2 col-tiles/wave
    {   // ---- layer 1 ----
        f32x4 acc[2][4];
        GEMM_PHASE(WT1, IN_CH, 4, ct0)
        __syncthreads();                       // all Hs(x) reads done
        AGG_PHASE(4, ct0, 0, true)
        __syncthreads();                       // Hs(h1) visible
    }
    {   // ---- layer 2 ----
        f32x4 acc[2][4];
        GEMM_PHASE(WT2, HID, 4, ct0)
        __syncthreads();
        AGG_PHASE(4, ct0, HID, true)
        __syncthreads();
    }
    {   // ---- layer 3 + min-pool (no Hs write) ----
        f32x4 acc[2][2];
        GEMM_PHASE(WT3, HID, 2, ct3)
        __syncthreads();                       // Hs reads done (BmT reuse safe)
        #pragma unroll
        for (int c = 0; c < 2; ++c) {
            s16x8 atf;
            TRANSPOSE(c, atf)
            float mn[4] = {1e30f, 1e30f, 1e30f, 1e30f};
            #pragma unroll
            for (int itn = 0; itn < 2; ++itn) {
                s16x8 btf = *(const s16x8*)(BT + (itn * 16 + lr) * 40 + lk * 8);
                f32x4 g = __builtin_amdgcn_mfma_f32_16x16x32_bf16(atf, btf, z4,
                                                                  0, 0, 0);
                #pragma unroll
                for (int jj = 0; jj < 4; ++jj) mn[jj] = fminf(mn[jj], g[jj]);
            }
            #pragma unroll
            for (int off = 1; off < 16; off <<= 1) {
                #pragma unroll
                for (int jj = 0; jj < 4; ++jj)
                    mn[jj] = fminf(mn[jj], __shfl_xor(mn[jj], off));
            }
            if (lr == 0) {
                int c0 = (ct3 + c) * 16 + lk * 4;
                #pragma unroll
                for (int jj = 0; jj < 4; ++jj)
                    BmT[c0 + jj] = mn[jj] + bias_s[2 * HID + c0 + jj];
            }
        }
    }
    __syncthreads();
    // prescale by KG-side dinv so the KG gather can skip a full pass
    if (t < OUT_CH) embed[(size_t)mol * OUT_CH + t] = BmT[t] * dinvk[mol];
#undef GEMM_PHASE
#undef TRANSPOSE
#undef AGG_PHASE
}

// ---------------------------------------------------------------------------
// KG graph. agg/GEMM commute (A-hat(XW) = (A-hat X)W), so both gathers run
// on 128-channel data: gather(embed)->GEMM1+relu, GEMM2->gather(+bias).
// ---------------------------------------------------------------------------
__global__ void kg_count(const int* __restrict__ kg_ei, int* __restrict__ degi) {
    int e = blockIdx.x * 256 + threadIdx.x;
    if (e < E_KG) atomicAdd(&degi[kg_ei[E_KG + e]], 1);
}

__global__ void kg_dinv(const int* __restrict__ degi, float* __restrict__ dinvk) {
    int i = blockIdx.x * 256 + threadIdx.x;
    if (i < KG_N) dinvk[i] = rsqrtf((float)(degi[i] + 1));   // +1 self loop
}

// single-block scan, register-blocked: 1024 thr x 10 elems, 2 barriers
__global__ __launch_bounds__(1024) void scan_kernel(const int* __restrict__ degi,
                                                    int* __restrict__ ptr, int n) {
    __shared__ int wsum[16];
    const int t = threadIdx.x;
    const int base = t * 10;
    int inc[10];
    int s = 0;
    #pragma unroll
    for (int i = 0; i < 10; ++i) {
        int idx = base + i;
        s += (idx < n) ? degi[idx] : 0;
        inc[i] = s;
    }
    const int lane = t & 63;
    int ps = s;
    #pragma unroll
    for (int off = 1; off < 64; off <<= 1) {
        int u = __shfl_up(ps, off);
        if (lane >= off) ps += u;
    }
    if (lane == 63) wsum[t >> 6] = ps;
    __syncthreads();
    if (t == 0) {
        int run = 0;
        #pragma unroll
        for (int k = 0; k < 16; ++k) { int x = wsum[k]; wsum[k] = run; run += x; }
        ptr[0] = 0;
    }
    __syncthreads();
    const int excl = wsum[t >> 6] + (ps - s);
    #pragma unroll
    for (int i = 0; i < 10; ++i) {
        int idx = base + i;
        if (idx < n) ptr[idx + 1] = excl + inc[i];
    }
}

__global__ void kg_fill(const int* __restrict__ kg_ei, const int* __restrict__ ptr,
                        int* __restrict__ cursor, int* __restrict__ csr) {
    int e = blockIdx.x * 256 + threadIdx.x;
    if (e < E_KG) {
        int s = kg_ei[e];
        int d = kg_ei[E_KG + e];
        int pos = atomicAdd(&cursor[d], 1);
        csr[ptr[d] + pos] = s;
    }
}

// out[n] = dinvk[n]*(xs[n] + sum_{s in in(n)} xs[s])  (+ bias); xs prescaled.
// 128 channels = 32 lanes x float4; 2 nodes per 64-thread block.
template <bool ADD_BIAS>
__global__ __launch_bounds__(64) void kg_gather(
    const float* __restrict__ xs, const float* __restrict__ dinvk,
    const int* __restrict__ ptr, const int* __restrict__ csr,
    const float* __restrict__ bias, float* __restrict__ out)
{
    const int sub = threadIdx.x >> 5;
    const int t   = threadIdx.x & 31;
    const int n   = blockIdx.x * 2 + sub;
    const float4* x4 = (const float4*)xs;
    const int e1 = ptr[n + 1];
    float4 acc = x4[(size_t)n * 32 + t];              // self (prescaled)
    for (int e = ptr[n]; e < e1; ++e) {
        int s = csr[e];
        float4 v = x4[(size_t)s * 32 + t];
        acc.x += v.x; acc.y += v.y; acc.z += v.z; acc.w += v.w;
    }
    const float dn = dinvk[n];
    float4 o;
    if (ADD_BIAS) {
        const float4 b = ((const float4*)bias)[t];
        o.x = fmaf(dn, acc.x, b.x); o.y = fmaf(dn, acc.y, b.y);
        o.z = fmaf(dn, acc.z, b.z); o.w = fmaf(dn, acc.w, b.w);
    } else {
        o.x = dn * acc.x; o.y = dn * acc.y; o.z = dn * acc.z; o.w = dn * acc.w;
    }
    ((float4*)out)[(size_t)n * 32 + t] = o;
}

// h1 = relu(G @ Wk1 + bk1)   (G: [N][128], Wk1: [128][256])
__global__ __launch_bounds__(256) void kg_gemm_relu(const float* __restrict__ X,
                                                    const float* __restrict__ W,
                                                    const float* __restrict__ bias,
                                                    float* __restrict__ Y) {
    __shared__ float es[4 * OUT_CH];
    const int t  = threadIdx.x;
    const int r0 = blockIdx.x * 4;
    if (t < 128) ((float4*)es)[t] = ((const float4*)(X + (size_t)r0 * OUT_CH))[t];
    __syncthreads();
    const int c = t;
    float a0 = 0.f, a1 = 0.f, a2 = 0.f, a3 = 0.f;
    for (int k = 0; k < OUT_CH; k += 4) {
        const float w0 = W[(k + 0) * HID + c], w1 = W[(k + 1) * HID + c],
                    w2 = W[(k + 2) * HID + c], w3 = W[(k + 3) * HID + c];
        float4 e0 = *(const float4*)&es[0 * OUT_CH + k];
        float4 e1 = *(const float4*)&es[1 * OUT_CH + k];
        float4 e2 = *(const float4*)&es[2 * OUT_CH + k];
        float4 e3 = *(const float4*)&es[3 * OUT_CH + k];
        a0 = fmaf(e0.x, w0, fmaf(e0.y, w1, fmaf(e0.z, w2, fmaf(e0.w, w3, a0))));
        a1 = fmaf(e1.x, w0, fmaf(e1.y, w1, fmaf(e1.z, w2, fmaf(e1.w, w3, a1))));
        a2 = fmaf(e2.x, w0, fmaf(e2.y, w1, fmaf(e2.z, w2, fmaf(e2.w, w3, a2))));
        a3 = fmaf(e3.x, w0, fmaf(e3.y, w1, fmaf(e3.z, w2, fmaf(e3.w, w3, a3))));
    }
    const float bc = bias[c];
    float v0 = a0 + bc, v1 = a1 + bc, v2 = a2 + bc, v3 = a3 + bc;
    Y[(size_t)(r0 + 0) * HID + c] = v0 > 0.f ? v0 : 0.f;
    Y[(size_t)(r0 + 1) * HID + c] = v1 > 0.f ? v1 : 0.f;
    Y[(size_t)(r0 + 2) * HID + c] = v2 > 0.f ? v2 : 0.f;
    Y[(size_t)(r0 + 3) * HID + c] = v3 > 0.f ? v3 : 0.f;
}

// xw2s = dinv * (h1 @ Wk2)   (h1: [N][256], Wk2: [256][128])
__global__ __launch_bounds__(256) void kg_gemm_scale(const float* __restrict__ X,
                                                     const float* __restrict__ W,
                                                     const float* __restrict__ dinvk,
                                                     float* __restrict__ Y) {
    __shared__ float es[8 * HID];
    const int t  = threadIdx.x;
    const int r0 = blockIdx.x * 8;
    {
        const float4* src = (const float4*)(X + (size_t)r0 * HID);
        float4* dst = (float4*)es;
        dst[t]       = src[t];
        dst[t + 256] = src[t + 256];
    }
    __syncthreads();
    const int c   = t & 127;
    const int rr0 = (t >> 7) * 4;
    float acc[4] = {0.f, 0.f, 0.f, 0.f};
    for (int k = 0; k < HID; k += 4) {
        const float w0 = W[(k + 0) * OUT_CH + c], w1 = W[(k + 1) * OUT_CH + c],
                    w2 = W[(k + 2) * OUT_CH + c], w3 = W[(k + 3) * OUT_CH + c];
        #pragma unroll
        for (int r = 0; r < 4; ++r) {
            float4 e = *(const float4*)&es[(rr0 + r) * HID + k];
            acc[r] = fmaf(e.x, w0, fmaf(e.y, w1, fmaf(e.z, w2, fmaf(e.w, w3, acc[r]))));
        }
    }
    #pragma unroll
    for (int r = 0; r < 4; ++r)
        Y[(size_t)(r0 + rr0 + r) * OUT_CH + c] = dinvk[r0 + rr0 + r] * acc[r];
}

// ---------------------------------------------------------------------------
extern "C" void kernel_launch(void* const* d_in, const int* in_sizes, int n_in,
                              void* d_out, int out_size, void* d_ws, size_t ws_size,
                              hipStream_t stream) {
    const float* mol_x  = (const float*)d_in[0];
    const int*   mol_ei = (const int*)  d_in[1];
    const int*   kg_ei  = (const int*)  d_in[2];
    const float* W1 = (const float*)d_in[3];  const float* b1 = (const float*)d_in[4];
    const float* W2 = (const float*)d_in[5];  const float* b2 = (const float*)d_in[6];
    const float* W3 = (const float*)d_in[7];  const float* b3 = (const float*)d_in[8];
    const float* Wk1 = (const float*)d_in[9];  const float* bk1 = (const float*)d_in[10];
    const float* Wk2 = (const float*)d_in[11]; const float* bk2 = (const float*)d_in[12];
    float* out = (float*)d_out;

    char* ws = (char*)d_ws;
    size_t off = 0;
    auto alloc = [&](size_t bytes) -> void* {
        void* p = ws + off;
        off += (bytes + 255) & ~(size_t)255;
        return p;
    };
    float* embed = (float*)alloc((size_t)M_MOLS * OUT_CH * 4);   // dinv-prescaled
    float* G     = (float*)alloc((size_t)KG_N * OUT_CH * 4);     // A-hat @ E
    float* h1    = (float*)alloc((size_t)KG_N * HID * 4);
    float* xw2s  = (float*)alloc((size_t)KG_N * OUT_CH * 4);     // dinv-prescaled
    int*   degi  = (int*)  alloc((size_t)KG_N * 4);
    float* dinvk = (float*)alloc((size_t)KG_N * 4);
    int*   ptr   = (int*)  alloc((size_t)(KG_N + 4) * 4);
    int*   cursor= (int*)  alloc((size_t)KG_N * 4);
    int*   csr   = (int*)  alloc((size_t)E_KG * 4);
    short* wt1   = (short*)alloc((size_t)IN_CH * HID * 2);       // [256][64]
    short* wt2   = (short*)alloc((size_t)HID * HID * 2);         // [256][256]
    short* wt3   = (short*)alloc((size_t)OUT_CH * HID * 2);      // [128][256]

    hipMemsetAsync(degi,   0, (size_t)KG_N * 4, stream);
    hipMemsetAsync(cursor, 0, (size_t)KG_N * 4, stream);

    // KG degree/CSR first (mol epilogue needs dinvk)
    kg_count<<<(E_KG + 255) / 256, 256, 0, stream>>>(kg_ei, degi);
    scan_kernel<<<1, 1024, 0, stream>>>(degi, ptr, KG_N);
    kg_dinv<<<(KG_N + 255) / 256, 256, 0, stream>>>(degi, dinvk);
    kg_fill<<<(E_KG + 255) / 256, 256, 0, stream>>>(kg_ei, ptr, cursor, csr);

    prep_wt<<<(IN_CH * HID + 255) / 256, 256, 0, stream>>>(W1, wt1, IN_CH, HID, IN_CH * HID);
    prep_wt<<<(HID * HID + 255) / 256, 256, 0, stream>>>(W2, wt2, HID, HID, HID * HID);
    prep_wt<<<(OUT_CH * HID + 255) / 256, 256, 0, stream>>>(W3, wt3, HID, OUT_CH, HID * OUT_CH);

    // Phase A: molecule GNN -> embed (prescaled by dinvk)
    mol_kernel<<<M_MOLS, 256, 0, stream>>>(mol_x, mol_ei, wt1, b1, wt2, b2, wt3, b3,
                                           dinvk, embed);

    // KG layer 1: G = A-hat @ E ; h1 = relu(G @ Wk1 + bk1)
    kg_gather<false><<<KG_N / 2, 64, 0, stream>>>(embed, dinvk, ptr, csr, nullptr, G);
    kg_gemm_relu<<<KG_N / 4, 256, 0, stream>>>(G, Wk1, bk1, h1);

    // KG layer 2: xw2s = dinv*(h1 @ Wk2) ; out = dinv*(xw2s + gather) + bk2
    kg_gemm_scale<<<KG_N / 8, 256, 0, stream>>>(h1, Wk2, dinvk, xw2s);
    kg_gather<true><<<KG_N / 2, 64, 0, stream>>>(xw2s, dinvk, ptr, csr, bk2, out);
}

// Round 5
// 511.086 us; speedup vs baseline: 4.1276x; 1.0863x over previous
//
#include <hip/hip_runtime.h>

#define M_MOLS  10000
#define NA      32     // atoms per molecule
#define E_MOL   64
#define IN_CH   64
#define OUT_CH  128
#define HID     256
#define E_KG    320000
#define KG_N    10000

typedef __attribute__((ext_vector_type(8))) short  s16x8;  // 8 bf16 (4 VGPR)
typedef __attribute__((ext_vector_type(4))) float  f32x4;

// RNE float -> bf16 bits (finite inputs only)
static __device__ __forceinline__ short f2bf(float f) {
    unsigned u = __float_as_uint(f);
    u += 0x7FFFu + ((u >> 16) & 1u);
    return (short)(u >> 16);
}
// v_cvt_pk_bf16_f32: dword = [bf16(lo), bf16(hi)] (RNE, same bits as f2bf)
#define CVTPK(dst, lo, hi) \
    asm("v_cvt_pk_bf16_f32 %0, %1, %2" : "=v"(dst) : "v"(lo), "v"(hi))

// ---------------------------------------------------------------------------
// Weight prep: WT[c][k] = bf16(W[k][c])
// ---------------------------------------------------------------------------
__global__ void prep_wt(const float* __restrict__ W, short* __restrict__ WT,
                        int K, int C, int total) {
    int idx = blockIdx.x * 256 + threadIdx.x;
    if (idx < total) {
        int c = idx / K, k = idx - c * K;
        WT[idx] = f2bf(W[k * C + c]);
    }
}

// ---------------------------------------------------------------------------
// Molecule GNN, all-MFMA. Round-5 changes vs round-4:
//  * transpose acc->atf via cvt_pk packing + 8 ds_bpermute (was 16 bperm +
//    8 sel + 24 f2bf VALU ops) — same RNE rounding, fewer LDS/VALU ops
//  * wave0-only adjacency build with in-wave lgkmcnt ordering; wave1 stages
//    bias: block barriers 10 -> 6
//  * unroll-2 ks-loops: 8 WT loads in flight to hide L2 latency
// Hs layout: [32][256] bf16, XOR-swizzled byte ^= (row&7)<<4.
// ---------------------------------------------------------------------------
__global__ __launch_bounds__(256, 4) void mol_kernel(
    const float* __restrict__ mol_x, const int* __restrict__ mol_ei,
    const short* __restrict__ WT1, const float* __restrict__ b1,
    const short* __restrict__ WT2, const float* __restrict__ b2,
    const short* __restrict__ WT3, const float* __restrict__ b3,
    const float* __restrict__ dinvk, float* __restrict__ embed)
{
    __shared__ short Hs[NA * HID];               // 16 KB
    __shared__ short BT[NA * 40];                // 2.5 KB  BT[i][s], 80B rows
    __shared__ float BmT[NA * NA];               // 4 KB (reused as minbuf)
    __shared__ float bias_s[2 * HID + OUT_CH];   // 2.56 KB
    __shared__ float dinv[NA];
    __shared__ int   ideg[NA];

    const int t    = threadIdx.x;
    const int mol  = blockIdx.x;
    const int lane = t & 63;
    const int wid  = t >> 6;
    const int lr   = lane & 15;
    const int lk   = lane >> 4;
    char* HsB = (char*)Hs;

    // bpermute addresses for the packed transpose (byte = srclane*4)
    const int addrA = ((((lane >> 4) & 1) << 5) + lr) << 2;
    const int addrB = addrA + 64;

    // ---- stage x -> Hs bf16 (all threads; cvt_pk packed, swizzled 16B) ----
    {
        const float4* src = (const float4*)(mol_x + (size_t)mol * (NA * IN_CH));
        float4 a = src[t * 2], b = src[t * 2 + 1];
        int4 v;
        CVTPK(v.x, a.x, a.y); CVTPK(v.y, a.z, a.w);
        CVTPK(v.z, b.x, b.y); CVTPK(v.w, b.z, b.w);
        int row = t >> 3, k0 = (t & 7) * 8;
        int byte = (row << 9) + (k0 << 1); byte ^= (row & 7) << 4;
        *(int4*)(HsB + byte) = v;
    }
    // ---- wave0: adjacency build (in-wave ordering, no block barriers) ----
    if (wid == 0) {
        float4 z = {0.f, 0.f, 0.f, 0.f};
        float4* B4 = (float4*)BmT;
        B4[lane] = z; B4[lane + 64] = z; B4[lane + 128] = z; B4[lane + 192] = z;
        const int* eb = mol_ei + (size_t)mol * (2 * E_MOL);
        int es_ = eb[lane], ed_ = eb[E_MOL + lane];
        if (lane < NA) ideg[lane] = 1;
        asm volatile("s_waitcnt lgkmcnt(0)" ::: "memory");
        atomicAdd(&ideg[ed_], 1);
        asm volatile("s_waitcnt lgkmcnt(0)" ::: "memory");
        if (lane < NA) dinv[lane] = rsqrtf((float)ideg[lane]);
        asm volatile("s_waitcnt lgkmcnt(0)" ::: "memory");
        atomicAdd(&BmT[ed_ * NA + es_], dinv[es_] * dinv[ed_]);
        if (lane < NA) atomicAdd(&BmT[lane * NA + lane], dinv[lane] * dinv[lane]);
        asm volatile("s_waitcnt lgkmcnt(0)" ::: "memory");
        // BT[i][s] = bf16(BmT[i][s]); 16 elems/lane, packed
        int i0 = lane >> 1, s0 = (lane & 1) * 16;
        #pragma unroll
        for (int j = 0; j < 4; ++j) {
            float4 f = *(const float4*)&BmT[i0 * NA + s0 + j * 4];
            int2 w;
            CVTPK(w.x, f.x, f.y); CVTPK(w.y, f.z, f.w);
            *(int2*)&BT[i0 * 40 + s0 + j * 4] = w;
        }
    } else if (wid == 1) {
        // wave1: stage bias (b1|b2|b3 -> bias_s)
        float4* d = (float4*)bias_s;
        d[lane]      = ((const float4*)b1)[lane];
        d[64 + lane] = ((const float4*)b2)[lane];
        if (lane < 32) d[128 + lane] = ((const float4*)b3)[lane];
    }
    __syncthreads();   // [1] Hs(x), BT, bias all valid

    const f32x4 z4 = {0.f, 0.f, 0.f, 0.f};

    // GEMM: acc[it][c] = tile(atoms it*16.., cols (ct0+c)*16..) of Hs @ W
#define GEMM_PHASE(WT, K, NCT, CT0)                                            \
    _Pragma("unroll")                                                          \
    for (int it = 0; it < 2; ++it)                                             \
        _Pragma("unroll")                                                      \
        for (int c = 0; c < NCT; ++c) acc[it][c] = z4;                         \
    _Pragma("unroll 2")                                                        \
    for (int ks = 0; ks < (K) / 32; ++ks) {                                    \
        s16x8 af[2];                                                           \
        _Pragma("unroll")                                                      \
        for (int it = 0; it < 2; ++it) {                                       \
            int row = it * 16 + lr;                                            \
            int byte = (row << 9) + ((ks * 32 + lk * 8) << 1);                 \
            byte ^= (row & 7) << 4;                                            \
            af[it] = *(const s16x8*)(HsB + byte);                              \
        }                                                                      \
        _Pragma("unroll")                                                      \
        for (int c = 0; c < NCT; ++c) {                                        \
            s16x8 bf = *(const s16x8*)((WT) +                                  \
                (size_t)(((CT0) + c) * 16 + lr) * (K) + ks * 32 + lk * 8);     \
            acc[0][c] = __builtin_amdgcn_mfma_f32_16x16x32_bf16(af[0], bf,     \
                                                               acc[0][c], 0, 0, 0); \
            acc[1][c] = __builtin_amdgcn_mfma_f32_16x16x32_bf16(af[1], bf,     \
                                                               acc[1][c], 0, 0, 0); \
        }                                                                      \
    }

    // packed transpose: acc[*][cIdx] -> atf (A^T[ch=lr][atoms lk*8..+7])
    // pack 4 f32 -> 2 dwords per acc-tile, then 8 bpermute + 4 cndmask
#define TRANSPOSE_PK(cIdx, atf)                                                \
    {                                                                          \
        int pk0A, pk1A, pk0B, pk1B;                                            \
        CVTPK(pk0A, acc[0][cIdx][0], acc[0][cIdx][1]);                         \
        CVTPK(pk1A, acc[0][cIdx][2], acc[0][cIdx][3]);                         \
        CVTPK(pk0B, acc[1][cIdx][0], acc[1][cIdx][1]);                         \
        CVTPK(pk1B, acc[1][cIdx][2], acc[1][cIdx][3]);                         \
        int d0A = __builtin_amdgcn_ds_bpermute(addrA, pk0A);                   \
        int d1A = __builtin_amdgcn_ds_bpermute(addrA, pk1A);                   \
        int d2A = __builtin_amdgcn_ds_bpermute(addrB, pk0A);                   \
        int d3A = __builtin_amdgcn_ds_bpermute(addrB, pk1A);                   \
        int d0B = __builtin_amdgcn_ds_bpermute(addrA, pk0B);                   \
        int d1B = __builtin_amdgcn_ds_bpermute(addrA, pk1B);                   \
        int d2B = __builtin_amdgcn_ds_bpermute(addrB, pk0B);                   \
        int d3B = __builtin_amdgcn_ds_bpermute(addrB, pk1B);                   \
        bool hi_ = (lk & 2);                                                   \
        union { int i[4]; s16x8 v; } u_;                                       \
        u_.i[0] = hi_ ? d0B : d0A; u_.i[1] = hi_ ? d1B : d1A;                  \
        u_.i[2] = hi_ ? d2B : d2A; u_.i[3] = hi_ ? d3B : d3A;                  \
        atf = u_.v;                                                            \
    }

    // AGG (layers 1,2): Hnext^T tile = atf @ btf; packed 8B Hs writes
#define AGG_PHASE(NCT, CT0, BOFF, RELU)                                        \
    _Pragma("unroll")                                                          \
    for (int c = 0; c < NCT; ++c) {                                            \
        s16x8 atf;                                                             \
        TRANSPOSE_PK(c, atf)                                                   \
        _Pragma("unroll")                                                      \
        for (int itn = 0; itn < 2; ++itn) {                                    \
            s16x8 btf = *(const s16x8*)(BT + (itn * 16 + lr) * 40 + lk * 8);   \
            f32x4 g = __builtin_amdgcn_mfma_f32_16x16x32_bf16(atf, btf, z4,    \
                                                              0, 0, 0);        \
            int c0 = ((CT0) + c) * 16 + lk * 4;                                \
            float v0 = g[0] + bias_s[(BOFF) + c0 + 0];                         \
            float v1 = g[1] + bias_s[(BOFF) + c0 + 1];                         \
            float v2 = g[2] + bias_s[(BOFF) + c0 + 2];                         \
            float v3 = g[3] + bias_s[(BOFF) + c0 + 3];                         \
            if (RELU) {                                                        \
                v0 = fmaxf(v0, 0.f); v1 = fmaxf(v1, 0.f);                      \
                v2 = fmaxf(v2, 0.f); v3 = fmaxf(v3, 0.f);                      \
            }                                                                  \
            int2 w_;                                                           \
            CVTPK(w_.x, v0, v1); CVTPK(w_.y, v2, v3);                          \
            int row = itn * 16 + lr;                                           \
            int byte = (row << 9) + (c0 << 1); byte ^= (row & 7) << 4;         \
            *(int2*)(HsB + byte) = w_;                                         \
        }                                                                      \
    }

    const int ct0 = wid * 4;       // layers 1,2: 4 col-tiles/wave
    const int ct3 = wid * 2;       // layer 3:    2 col-tiles/wave
    {   // ---- layer 1 ----
        f32x4 acc[2][4];
        GEMM_PHASE(WT1, IN_CH, 4, ct0)
        __syncthreads();                       // [2] Hs(x) reads done
        AGG_PHASE(4, ct0, 0, true)
        __syncthreads();                       // [3] Hs(h1) visible
    }
    {   // ---- layer 2 ----
        f32x4 acc[2][4];
        GEMM_PHASE(WT2, HID, 4, ct0)
        __syncthreads();                       // [4]
        AGG_PHASE(4, ct0, HID, true)
        __syncthreads();                       // [5]
    }
    {   // ---- layer 3 + min-pool (writes BmT only) ----
        f32x4 acc[2][2];
        GEMM_PHASE(WT3, HID, 2, ct3)
        #pragma unroll
        for (int c = 0; c < 2; ++c) {
            s16x8 atf;
            TRANSPOSE_PK(c, atf)
            float mn[4] = {1e30f, 1e30f, 1e30f, 1e30f};
            #pragma unroll
            for (int itn = 0; itn < 2; ++itn) {
                s16x8 btf = *(const s16x8*)(BT + (itn * 16 + lr) * 40 + lk * 8);
                f32x4 g = __builtin_amdgcn_mfma_f32_16x16x32_bf16(atf, btf, z4,
                                                                  0, 0, 0);
                #pragma unroll
                for (int jj = 0; jj < 4; ++jj) mn[jj] = fminf(mn[jj], g[jj]);
            }
            #pragma unroll
            for (int off = 1; off < 16; off <<= 1) {
                #pragma unroll
                for (int jj = 0; jj < 4; ++jj)
                    mn[jj] = fminf(mn[jj], __shfl_xor(mn[jj], off));
            }
            if (lr == 0) {
                int c0 = (ct3 + c) * 16 + lk * 4;
                #pragma unroll
                for (int jj = 0; jj < 4; ++jj)
                    BmT[c0 + jj] = mn[jj] + bias_s[2 * HID + c0 + jj];
            }
        }
    }
    __syncthreads();   // [6]
    // prescale by KG-side dinv so the KG gather can skip a full pass
    if (t < OUT_CH) embed[(size_t)mol * OUT_CH + t] = BmT[t] * dinvk[mol];
#undef GEMM_PHASE
#undef TRANSPOSE_PK
#undef AGG_PHASE
}

// ---------------------------------------------------------------------------
// KG graph. agg/GEMM commute: gather(embed)->GEMM1+relu, GEMM2->gather.
// ---------------------------------------------------------------------------
__global__ void kg_count(const int* __restrict__ kg_ei, int* __restrict__ degi) {
    int e = blockIdx.x * 256 + threadIdx.x;
    if (e < E_KG) atomicAdd(&degi[kg_ei[E_KG + e]], 1);
}

// single-block scan (register-blocked) + dinv fused
__global__ __launch_bounds__(1024) void scan_kernel(const int* __restrict__ degi,
                                                    int* __restrict__ ptr,
                                                    float* __restrict__ dinvk, int n) {
    __shared__ int wsum[16];
    const int t = threadIdx.x;
    const int base = t * 10;
    int inc[10];
    int s = 0;
    #pragma unroll
    for (int i = 0; i < 10; ++i) {
        int idx = base + i;
        int d = (idx < n) ? degi[idx] : 0;
        if (idx < n) dinvk[idx] = rsqrtf((float)(d + 1));   // +1 self loop
        s += d;
        inc[i] = s;
    }
    const int lane = t & 63;
    int ps = s;
    #pragma unroll
    for (int off = 1; off < 64; off <<= 1) {
        int u = __shfl_up(ps, off);
        if (lane >= off) ps += u;
    }
    if (lane == 63) wsum[t >> 6] = ps;
    __syncthreads();
    if (t == 0) {
        int run = 0;
        #pragma unroll
        for (int k = 0; k < 16; ++k) { int x = wsum[k]; wsum[k] = run; run += x; }
        ptr[0] = 0;
    }
    __syncthreads();
    const int excl = wsum[t >> 6] + (ps - s);
    #pragma unroll
    for (int i = 0; i < 10; ++i) {
        int idx = base + i;
        if (idx < n) ptr[idx + 1] = excl + inc[i];
    }
}

__global__ void kg_fill(const int* __restrict__ kg_ei, const int* __restrict__ ptr,
                        int* __restrict__ cursor, int* __restrict__ csr) {
    int e = blockIdx.x * 256 + threadIdx.x;
    if (e < E_KG) {
        int s = kg_ei[e];
        int d = kg_ei[E_KG + e];
        int pos = atomicAdd(&cursor[d], 1);
        csr[ptr[d] + pos] = s;
    }
}

// out[n] = dinvk[n]*(xs[n] + sum_in xs[s]) (+bias); xs prescaled by dinv[src].
// 128 ch = 32 lanes x float4; 2 nodes / 64-thread block; 4-way edge chunks.
template <bool ADD_BIAS>
__global__ __launch_bounds__(64) void kg_gather(
    const float* __restrict__ xs, const float* __restrict__ dinvk,
    const int* __restrict__ ptr, const int* __restrict__ csr,
    const float* __restrict__ bias, float* __restrict__ out)
{
    const int sub = threadIdx.x >> 5;
    const int t   = threadIdx.x & 31;
    const int n   = blockIdx.x * 2 + sub;
    const float4* x4 = (const float4*)xs;
    int e = ptr[n];
    const int e1 = ptr[n + 1];
    float4 acc = x4[(size_t)n * 32 + t];              // self (prescaled)
    for (; e + 4 <= e1; e += 4) {
        int s0 = csr[e], s1 = csr[e + 1], s2 = csr[e + 2], s3 = csr[e + 3];
        float4 v0 = x4[(size_t)s0 * 32 + t], v1 = x4[(size_t)s1 * 32 + t];
        float4 v2 = x4[(size_t)s2 * 32 + t], v3 = x4[(size_t)s3 * 32 + t];
        acc.x += v0.x + v1.x + v2.x + v3.x;
        acc.y += v0.y + v1.y + v2.y + v3.y;
        acc.z += v0.z + v1.z + v2.z + v3.z;
        acc.w += v0.w + v1.w + v2.w + v3.w;
    }
    for (; e < e1; ++e) {
        int s = csr[e];
        float4 v = x4[(size_t)s * 32 + t];
        acc.x += v.x; acc.y += v.y; acc.z += v.z; acc.w += v.w;
    }
    const float dn = dinvk[n];
    float4 o;
    if (ADD_BIAS) {
        const float4 b = ((const float4*)bias)[t];
        o.x = fmaf(dn, acc.x, b.x); o.y = fmaf(dn, acc.y, b.y);
        o.z = fmaf(dn, acc.z, b.z); o.w = fmaf(dn, acc.w, b.w);
    } else {
        o.x = dn * acc.x; o.y = dn * acc.y; o.z = dn * acc.z; o.w = dn * acc.w;
    }
    ((float4*)out)[(size_t)n * 32 + t] = o;
}

// h1 = relu(G @ Wk1 + bk1)   (G: [N][128], Wk1: [128][256])
__global__ __launch_bounds__(256) void kg_gemm_relu(const float* __restrict__ X,
                                                    const float* __restrict__ W,
                                                    const float* __restrict__ bias,
                                                    float* __restrict__ Y) {
    __shared__ float es[4 * OUT_CH];
    const int t  = threadIdx.x;
    const int r0 = blockIdx.x * 4;
    if (t < 128) ((float4*)es)[t] = ((const float4*)(X + (size_t)r0 * OUT_CH))[t];
    __syncthreads();
    const int c = t;
    float a0 = 0.f, a1 = 0.f, a2 = 0.f, a3 = 0.f;
    #pragma unroll 4
    for (int k = 0; k < OUT_CH; k += 4) {
        const float w0 = W[(k + 0) * HID + c], w1 = W[(k + 1) * HID + c],
                    w2 = W[(k + 2) * HID + c], w3 = W[(k + 3) * HID + c];
        float4 e0 = *(const float4*)&es[0 * OUT_CH + k];
        float4 e1 = *(const float4*)&es[1 * OUT_CH + k];
        float4 e2 = *(const float4*)&es[2 * OUT_CH + k];
        float4 e3 = *(const float4*)&es[3 * OUT_CH + k];
        a0 = fmaf(e0.x, w0, fmaf(e0.y, w1, fmaf(e0.z, w2, fmaf(e0.w, w3, a0))));
        a1 = fmaf(e1.x, w0, fmaf(e1.y, w1, fmaf(e1.z, w2, fmaf(e1.w, w3, a1))));
        a2 = fmaf(e2.x, w0, fmaf(e2.y, w1, fmaf(e2.z, w2, fmaf(e2.w, w3, a2))));
        a3 = fmaf(e3.x, w0, fmaf(e3.y, w1, fmaf(e3.z, w2, fmaf(e3.w, w3, a3))));
    }
    const float bc = bias[c];
    float v0 = a0 + bc, v1 = a1 + bc, v2 = a2 + bc, v3 = a3 + bc;
    Y[(size_t)(r0 + 0) * HID + c] = v0 > 0.f ? v0 : 0.f;
    Y[(size_t)(r0 + 1) * HID + c] = v1 > 0.f ? v1 : 0.f;
    Y[(size_t)(r0 + 2) * HID + c] = v2 > 0.f ? v2 : 0.f;
    Y[(size_t)(r0 + 3) * HID + c] = v3 > 0.f ? v3 : 0.f;
}

// xw2s = dinv * (h1 @ Wk2)   (h1: [N][256], Wk2: [256][128])
__global__ __launch_bounds__(256) void kg_gemm_scale(const float* __restrict__ X,
                                                     const float* __restrict__ W,
                                                     const float* __restrict__ dinvk,
                                                     float* __restrict__ Y) {
    __shared__ float es[8 * HID];
    const int t  = threadIdx.x;
    const int r0 = blockIdx.x * 8;
    {
        const float4* src = (const float4*)(X + (size_t)r0 * HID);
        float4* dst = (float4*)es;
        dst[t]       = src[t];
        dst[t + 256] = src[t + 256];
    }
    __syncthreads();
    const int c   = t & 127;
    const int rr0 = (t >> 7) * 4;
    float acc[4] = {0.f, 0.f, 0.f, 0.f};
    #pragma unroll 4
    for (int k = 0; k < HID; k += 4) {
        const float w0 = W[(k + 0) * OUT_CH + c], w1 = W[(k + 1) * OUT_CH + c],
                    w2 = W[(k + 2) * OUT_CH + c], w3 = W[(k + 3) * OUT_CH + c];
        #pragma unroll
        for (int r = 0; r < 4; ++r) {
            float4 e = *(const float4*)&es[(rr0 + r) * HID + k];
            acc[r] = fmaf(e.x, w0, fmaf(e.y, w1, fmaf(e.z, w2, fmaf(e.w, w3, acc[r]))));
        }
    }
    #pragma unroll
    for (int r = 0; r < 4; ++r)
        Y[(size_t)(r0 + rr0 + r) * OUT_CH + c] = dinvk[r0 + rr0 + r] * acc[r];
}

// ---------------------------------------------------------------------------
extern "C" void kernel_launch(void* const* d_in, const int* in_sizes, int n_in,
                              void* d_out, int out_size, void* d_ws, size_t ws_size,
                              hipStream_t stream) {
    const float* mol_x  = (const float*)d_in[0];
    const int*   mol_ei = (const int*)  d_in[1];
    const int*   kg_ei  = (const int*)  d_in[2];
    const float* W1 = (const float*)d_in[3];  const float* b1 = (const float*)d_in[4];
    const float* W2 = (const float*)d_in[5];  const float* b2 = (const float*)d_in[6];
    const float* W3 = (const float*)d_in[7];  const float* b3 = (const float*)d_in[8];
    const float* Wk1 = (const float*)d_in[9];  const float* bk1 = (const float*)d_in[10];
    const float* Wk2 = (const float*)d_in[11]; const float* bk2 = (const float*)d_in[12];
    float* out = (float*)d_out;

    char* ws = (char*)d_ws;
    size_t off = 0;
    auto alloc = [&](size_t bytes) -> void* {
        void* p = ws + off;
        off += (bytes + 255) & ~(size_t)255;
        return p;
    };
    float* embed = (float*)alloc((size_t)M_MOLS * OUT_CH * 4);   // dinv-prescaled
    float* G     = (float*)alloc((size_t)KG_N * OUT_CH * 4);     // A-hat @ E
    float* h1    = (float*)alloc((size_t)KG_N * HID * 4);
    float* xw2s  = (float*)alloc((size_t)KG_N * OUT_CH * 4);     // dinv-prescaled
    int*   degi  = (int*)  alloc((size_t)KG_N * 4);
    float* dinvk = (float*)alloc((size_t)KG_N * 4);
    int*   ptr   = (int*)  alloc((size_t)(KG_N + 4) * 4);
    int*   cursor= (int*)  alloc((size_t)KG_N * 4);
    int*   csr   = (int*)  alloc((size_t)E_KG * 4);
    short* wt1   = (short*)alloc((size_t)IN_CH * HID * 2);       // [256][64]
    short* wt2   = (short*)alloc((size_t)HID * HID * 2);         // [256][256]
    short* wt3   = (short*)alloc((size_t)OUT_CH * HID * 2);      // [128][256]

    hipMemsetAsync(degi,   0, (size_t)KG_N * 4, stream);
    hipMemsetAsync(cursor, 0, (size_t)KG_N * 4, stream);

    // KG degree/CSR first (mol epilogue needs dinvk)
    kg_count<<<(E_KG + 255) / 256, 256, 0, stream>>>(kg_ei, degi);
    scan_kernel<<<1, 1024, 0, stream>>>(degi, ptr, dinvk, KG_N);
    kg_fill<<<(E_KG + 255) / 256, 256, 0, stream>>>(kg_ei, ptr, cursor, csr);

    prep_wt<<<(IN_CH * HID + 255) / 256, 256, 0, stream>>>(W1, wt1, IN_CH, HID, IN_CH * HID);
    prep_wt<<<(HID * HID + 255) / 256, 256, 0, stream>>>(W2, wt2, HID, HID, HID * HID);
    prep_wt<<<(OUT_CH * HID + 255) / 256, 256, 0, stream>>>(W3, wt3, HID, OUT_CH, HID * OUT_CH);

    // Phase A: molecule GNN -> embed (prescaled by dinvk)
    mol_kernel<<<M_MOLS, 256, 0, stream>>>(mol_x, mol_ei, wt1, b1, wt2, b2, wt3, b3,
                                           dinvk, embed);

    // KG layer 1: G = A-hat @ E ; h1 = relu(G @ Wk1 + bk1)
    kg_gather<false><<<KG_N / 2, 64, 0, stream>>>(embed, dinvk, ptr, csr, nullptr, G);
    kg_gemm_relu<<<KG_N / 4, 256, 0, stream>>>(G, Wk1, bk1, h1);

    // KG layer 2: xw2s = dinv*(h1 @ Wk2) ; out = dinv*(xw2s + gather) + bk2
    kg_gemm_scale<<<KG_N / 8, 256, 0, stream>>>(h1, Wk2, dinvk, xw2s);
    kg_gather<true><<<KG_N / 2, 64, 0, stream>>>(xw2s, dinvk, ptr, csr, bk2, out);
}